// Round 7
// baseline (259.535 us; speedup 1.0000x reference)
//
#include <hip/hip_runtime.h>
#include <hip/hip_fp16.h>
#include <math.h>

#define BB 512
#define SS 100
#define DE 150
#define DM 300   // 2*D_E (also == D_IN)
#define LL 101
#define NH 2

// ---- ws layout (float offsets) ----
#define WS_CLS    0        // [300]
#define WS_QK     320      // [2][300]
#define WS_S0     960      // [2]
#define WS_CPOS   964      // [100][2]
#define WS_CVEC   1200     // [300]
#define WS_COLSUM 1536     // [300]
#define WS_CST0   1856     // [2]
#define WS_STATS  1860     // [0]=a1 [1]=beta1
#define WS_PART1  1920     // [64][2]
#define WS_PART2  2048     // [64][2]
#define WS_G      2176     // [1200][2]
#define WS_Q0     4608     // [2][300]
#define WS_P3     5248     // [15][2][300]
#define WS_MSA    14336                     // [512][600]
#define WS_Y1     (WS_MSA + 512*600)        // [512][300]

// ---------------- kC1: q0 | Wp1 partials | cls | G=fc1@fc2 ----------------
__global__ void kC1(const float* __restrict__ pos, const float* __restrict__ cle,
                    const float* __restrict__ Wq, const float* __restrict__ Wp1,
                    const float* __restrict__ f1W, const float* __restrict__ f2W,
                    const float* __restrict__ f1b, const float* __restrict__ f2b,
                    float* __restrict__ ws) {
  __shared__ float cls[DM];
  int b = blockIdx.x, tid = threadIdx.x;
  if (b < 18) {
    for (int i = tid; i < DM; i += 256) cls[i] = (i < DE) ? cle[i] : pos[i - DE];
    __syncthreads();
  }
  if (b < 3) {
    int idx = b * 256 + tid;
    if (idx < NH * DM) {
      int h = idx / DM, e = idx % DM;
      const float* w = Wq + h * DM * DM + e;
      float acc = 0.f;
      for (int d = 0; d < DM; ++d) acc += cls[d] * w[d * DM];
      ws[WS_Q0 + idx] = acc;
    }
  } else if (b < 18) {
    int kb = b - 3;
    for (int n = tid; n < DM; n += 256) {
      float cs = 0.f, cv = 0.f;
      for (int k = kb * 60; k < kb * 60 + 60; ++k) {
        float w = Wp1[k * 300 + n];
        if (k < 600) cs += w; else cv += cls[k - 600] * w;
      }
      ws[WS_P3 + kb * 600 + n] = cs;
      ws[WS_P3 + kb * 600 + 300 + n] = cv;
    }
  } else if (b == 18) {
    for (int i = tid; i < DM; i += 256)
      ws[WS_CLS + i] = (i < DE) ? cle[i] : pos[i - DE];
  } else {
    int t = (b - 19) * 256 + tid;
    if (t < 2400) {
      int k = t >> 1, c = t & 1;
      const float* r = f1W + k * 512;
      float acc = 0.f;
      for (int m = 0; m < 512; ++m) acc += r[m] * f2W[m * 2 + c];
      ws[WS_G + t] = acc;
    } else if (t < 2402) {
      int c = t - 2400;
      float acc = f2b[c];
      for (int m = 0; m < 512; ++m) acc += f1b[m] * f2W[m * 2 + c];
      ws[WS_CST0 + c] = acc;
    }
  }
}

// ---------------- kC2: qk[h][d] = Wk[h][d][:] . q0[h][:] (wave per output) ----------------
__global__ void kC2(const float* __restrict__ Wk, float* __restrict__ ws) {
  __shared__ float q0s[NH * DM];
  int tid = threadIdx.x;
  for (int i = tid; i < NH * DM; i += 256) q0s[i] = ws[WS_Q0 + i];
  __syncthreads();
  int wave = tid >> 6, lane = tid & 63;
  int idx = blockIdx.x * 4 + wave;            // < 600
  int h = idx / DM, d = idx % DM;
  const float* w = Wk + h * DM * DM + d * DM;
  const float* q = q0s + h * DM;
  float acc = 0.f;
  for (int e = lane; e < DM; e += 64) acc += w[e] * q[e];
  for (int o = 32; o; o >>= 1) acc += __shfl_xor(acc, o);
  if (!lane) ws[WS_QK + idx] = acc;
}

// ---------------- kC3: cpos | s0 | combine(colsum,cvec) ----------------
__global__ void kC3(const float* __restrict__ pos, const float* __restrict__ bp1,
                    float* __restrict__ ws) {
  int b = blockIdx.x, tid = threadIdx.x;
  int wave = tid >> 6, lane = tid & 63;
  if (b < 50) {
    int idx = b * 4 + wave;                   // < 200, = tt*2+h
    int tt = idx >> 1, h = idx & 1;
    const float* pr = pos + (tt + 1) * DE;
    const float* qk = ws + WS_QK + h * DM + DE;
    float acc = 0.f;
    for (int j = lane; j < DE; j += 64) acc += pr[j] * qk[j];
    for (int o = 32; o; o >>= 1) acc += __shfl_xor(acc, o);
    if (!lane) ws[WS_CPOS + idx] = acc;
  } else if (b == 50) {
    if (wave < NH) {
      float acc = 0.f;
      for (int d = lane; d < DM; d += 64) acc += ws[WS_CLS + d] * ws[WS_QK + wave * DM + d];
      for (int o = 32; o; o >>= 1) acc += __shfl_xor(acc, o);
      if (!lane) ws[WS_S0 + wave] = acc;
    }
  } else {
    for (int n = tid; n < DM; n += 256) {
      float cs = 0.f, cv = bp1[n];
      for (int p = 0; p < 15; ++p) {
        cs += ws[WS_P3 + p * 600 + n];
        cv += ws[WS_P3 + p * 600 + 300 + n];
      }
      ws[WS_COLSUM + n] = cs;
      ws[WS_CVEC + n] = cv;
    }
  }
}

// ---------------- kA: fused h-GEMM -> scores -> softmax -> zbar -> msa ----------------
// 512 threads (8 waves); 2 blocks/CU -> 16 waves/CU.
// Phase 1: Wp staged fp16 in LDS; each thread reads its 8 cols as ONE ds_read_b128
// per k-step (10x fewer LDS instrs than round 6's scalar b32 reads).
// LDS: hb 30,400 + aux 5,120 + zb 2,400 = 37,920 B.
__launch_bounds__(512, 4)
__global__ void kA(const float* __restrict__ x, const float* __restrict__ Wp,
                   const float* __restrict__ bp, const float* __restrict__ pos,
                   const float* __restrict__ Wv, float* __restrict__ ws) {
  __shared__ __half hb[SS][DE + 2];
  __shared__ float aux[1280];
  __shared__ float zb[NH * DM];
  int b = blockIdx.x, tid = threadIdx.x;
  int tx = tid % 20, ty = tid / 20;   // tx: 8-col group; ty: row group (ty<25 active)
  bool act = (ty < 25);
  int c0 = tx * 8;

  // ---- phase 1: h[b] = relu(x[b] @ Wp + bp) ----
  float acc[4][8];
#pragma unroll
  for (int i = 0; i < 4; ++i)
#pragma unroll
    for (int j = 0; j < 8; ++j) acc[i][j] = 0.f;
  const float* xb = x + b * SS * DM;
  int rows[4];
#pragma unroll
  for (int i = 0; i < 4; ++i) rows[i] = act ? (ty + 25 * i) : 99;

  __half2* auxh2 = (__half2*)aux;

  for (int kc = 0; kc < 296; kc += 8) {
    // stage Wp[kc..kc+8) as fp16: aux half2 layout [kk][80]
    for (int i = tid; i < 8 * 80; i += 512) {
      int kk = i / 80, cp = i % 80, c = cp * 2;
      const float* wr = Wp + (kc + kk) * DE;
      float w0 = (c < DE) ? wr[c] : 0.f;
      float w1 = (c + 1 < DE) ? wr[c + 1] : 0.f;
      auxh2[i] = __floats2half2_rn(w0, w1);
    }
    __syncthreads();
    float a[4][8];
#pragma unroll
    for (int i = 0; i < 4; ++i) {
      const float* xr = xb + rows[i] * DM + kc;
      float4 q0 = *(const float4*)xr;
      float4 q1 = *(const float4*)(xr + 4);
      a[i][0] = q0.x; a[i][1] = q0.y; a[i][2] = q0.z; a[i][3] = q0.w;
      a[i][4] = q1.x; a[i][5] = q1.y; a[i][6] = q1.z; a[i][7] = q1.w;
    }
#pragma unroll
    for (int kk = 0; kk < 8; ++kk) {
      float4 f = *(const float4*)&aux[kk * 80 + tx * 4];   // 8 halves = this thread's 8 cols
      const __half2* hp = (const __half2*)&f;
      float2 b01 = __half22float2(hp[0]);
      float2 b23 = __half22float2(hp[1]);
      float2 b45 = __half22float2(hp[2]);
      float2 b67 = __half22float2(hp[3]);
      float bf[8] = {b01.x, b01.y, b23.x, b23.y, b45.x, b45.y, b67.x, b67.y};
#pragma unroll
      for (int i = 0; i < 4; ++i)
#pragma unroll
        for (int j = 0; j < 8; ++j) acc[i][j] = fmaf(a[i][kk], bf[j], acc[i][j]);
    }
    __syncthreads();
  }
  { // tail: kc = 296, 4 k-steps
    const int kc = 296;
    for (int i = tid; i < 4 * 80; i += 512) {
      int kk = i / 80, cp = i % 80, c = cp * 2;
      const float* wr = Wp + (kc + kk) * DE;
      float w0 = (c < DE) ? wr[c] : 0.f;
      float w1 = (c + 1 < DE) ? wr[c + 1] : 0.f;
      auxh2[i] = __floats2half2_rn(w0, w1);
    }
    __syncthreads();
    float a[4][4];
#pragma unroll
    for (int i = 0; i < 4; ++i) {
      const float* xr = xb + rows[i] * DM + kc;
      float4 q0 = *(const float4*)xr;
      a[i][0] = q0.x; a[i][1] = q0.y; a[i][2] = q0.z; a[i][3] = q0.w;
    }
#pragma unroll
    for (int kk = 0; kk < 4; ++kk) {
      float4 f = *(const float4*)&aux[kk * 80 + tx * 4];
      const __half2* hp = (const __half2*)&f;
      float2 b01 = __half22float2(hp[0]);
      float2 b23 = __half22float2(hp[1]);
      float2 b45 = __half22float2(hp[2]);
      float2 b67 = __half22float2(hp[3]);
      float bf[8] = {b01.x, b01.y, b23.x, b23.y, b45.x, b45.y, b67.x, b67.y};
#pragma unroll
      for (int i = 0; i < 4; ++i)
#pragma unroll
        for (int j = 0; j < 8; ++j) acc[i][j] = fmaf(a[i][kk], bf[j], acc[i][j]);
    }
    __syncthreads();
  }
  // write hb (packed fp16, one b128 per row)
  if (act && tx < 19) {
    float bpv[8];
#pragma unroll
    for (int k = 0; k < 8; ++k) {
      int c = c0 + k;
      bpv[k] = (c < DE) ? bp[c] : 0.f;
    }
#pragma unroll
    for (int i = 0; i < 4; ++i) {
      int r = rows[i];
      __half2 ho[4];
#pragma unroll
      for (int p = 0; p < 4; ++p) {
        float v0 = acc[i][2 * p] + bpv[2 * p];
        float v1 = acc[i][2 * p + 1] + bpv[2 * p + 1];
        ho[p] = __floats2half2_rn(v0 > 0.f ? v0 : 0.f, v1 > 0.f ? v1 : 0.f);
      }
      *(float4*)&hb[r][c0] = *(const float4*)ho;
    }
  }
  // reload aux: qk first-halves + cls
  for (int i = tid; i < DM; i += 512) {
    aux[i] = ws[WS_QK + (i / DE) * DM + (i % DE)];
    aux[DM + i] = ws[WS_CLS + i];
  }
  __syncthreads();

  // ---- phase 2: scores ----
  if (tid < NH * SS) {
    int hh = tid / SS, tt = tid % SS;
    float s = 0.f;
    for (int j = 0; j < DE; ++j) s += __half2float(hb[tt][j]) * aux[hh * DE + j];
    aux[600 + hh * LL + tt + 1] = s + ws[WS_CPOS + tt * NH + hh];
  } else if (tid < NH * SS + NH) {
    int hh = tid - NH * SS;
    aux[600 + hh * LL] = ws[WS_S0 + hh];
  }
  __syncthreads();

  // ---- phase 3: softmax (one wave per head) ----
  int wave = tid >> 6, lane = tid & 63;
  if (wave < NH) {
    float v0 = aux[600 + wave * LL + lane];
    float v1 = (lane + 64 < LL) ? aux[600 + wave * LL + lane + 64] : -1e30f;
    float m = fmaxf(v0, v1);
    for (int o = 32; o; o >>= 1) m = fmaxf(m, __shfl_xor(m, o));
    float e0 = expf(v0 - m);
    float e1 = (lane + 64 < LL) ? expf(v1 - m) : 0.f;
    float s = e0 + e1;
    for (int o = 32; o; o >>= 1) s += __shfl_xor(s, o);
    float inv = 1.f / s;
    aux[802 + wave * LL + lane] = e0 * inv;
    if (lane + 64 < LL) aux[802 + wave * LL + lane + 64] = e1 * inv;
  }
  __syncthreads();

  // ---- phase 4: zbar[h][d] = sum_t p[t]*z[b,t,d]  (into LDS) ----
  for (int o = tid; o < NH * DM; o += 512) {
    int hh = o / DM, d = o % DM;
    const float* p = &aux[802 + hh * LL];
    float acc2 = p[0] * aux[DM + d];
    if (d < DE) {
      for (int t = 1; t <= SS; ++t) acc2 += p[t] * __half2float(hb[t - 1][d]);
    } else {
      int dd = d - DE;
      for (int t = 1; t <= SS; ++t) acc2 += p[t] * pos[t * DE + dd];
    }
    zb[o] = acc2;
  }
  __syncthreads();

  // ---- phase 5: msa[b] = zb @ Wv (per head) ----
  for (int e = tid; e < NH * DM; e += 512) {
    int hh = e / DM, ee = e % DM;
    const float* wv = Wv + hh * DM * DM + ee;
    const float* z = zb + hh * DM;
    float s0 = 0.f, s1 = 0.f;
    for (int d = 0; d < DM; d += 2) {
      s0 += z[d] * wv[d * DM];
      s1 += z[d + 1] * wv[(d + 1) * DM];
    }
    ws[WS_MSA + b * 600 + e] = s0 + s1;
  }
}

// ---------------- k4a: bn1 channel-0 partial stats ----------------
__global__ void k4a(float* __restrict__ ws) {
  int tid = threadIdx.x, bid = blockIdx.x;
  float s = 0.f, ss = 0.f;
  for (int i = bid * 256 + tid; i < BB * 600; i += 64 * 256) {
    float v = ws[WS_MSA + i];
    s += v; ss += v * v;
  }
  for (int o = 32; o; o >>= 1) { s += __shfl_xor(s, o); ss += __shfl_xor(ss, o); }
  __shared__ float sh[2][4];
  int wave = tid >> 6, lane = tid & 63;
  if (!lane) { sh[0][wave] = s; sh[1][wave] = ss; }
  __syncthreads();
  if (!tid) {
    float S = 0.f, SS2 = 0.f;
    for (int w = 0; w < 4; ++w) { S += sh[0][w]; SS2 += sh[1][w]; }
    ws[WS_PART1 + bid * 2] = S;
    ws[WS_PART1 + bid * 2 + 1] = SS2;
  }
}

// ---------------- k5: bn1 finalize (inline) + y1 = relu(a1*(msa@Wp1[:600]) + ...) ----------------
__launch_bounds__(256)
__global__ void k5(const float* __restrict__ Wp1, const float* __restrict__ g1,
                   const float* __restrict__ b1, float* __restrict__ ws) {
  __shared__ float ab[2][600];
  __shared__ float s_a1, s_b1;
  int b0 = blockIdx.x * 2, tid = threadIdx.x;
  for (int i = tid; i < 2 * 600; i += 256) ab[i / 600][i % 600] = ws[WS_MSA + b0 * 600 + i];
  if (tid < 64) {
    float s = ws[WS_PART1 + tid * 2], ss = ws[WS_PART1 + tid * 2 + 1];
    for (int o = 32; o; o >>= 1) { s += __shfl_xor(s, o); ss += __shfl_xor(ss, o); }
    if (!tid) {
      float n = (float)(BB * 600);
      float mean = s / n, var = ss / n - mean * mean;
      float a = (1.f / sqrtf(var + 1e-5f)) * g1[0];
      s_a1 = a; s_b1 = b1[0] - a * mean;
      if (blockIdx.x == 0) { ws[WS_STATS + 0] = a; ws[WS_STATS + 1] = s_b1; }
    }
  }
  __syncthreads();
  float a1 = s_a1, beta1 = s_b1;
  for (int n = tid; n < DM; n += 256) {
    float acc0 = 0.f, acc1 = 0.f;
    for (int k = 0; k < 600; ++k) {
      float w = Wp1[k * 300 + n];
      acc0 += ab[0][k] * w;
      acc1 += ab[1][k] * w;
    }
    float c = beta1 * ws[WS_COLSUM + n] + ws[WS_CVEC + n];
    float v0 = a1 * acc0 + c, v1 = a1 * acc1 + c;
    ws[WS_Y1 + b0 * 300 + n] = v0 > 0.f ? v0 : 0.f;
    ws[WS_Y1 + (b0 + 1) * 300 + n] = v1 > 0.f ? v1 : 0.f;
  }
}

// ---------------- k6a: bn2 channel-0 partial stats ----------------
__global__ void k6a(float* __restrict__ ws) {
  int tid = threadIdx.x, bid = blockIdx.x;
  float s = 0.f, ss = 0.f;
  for (int i = bid * 256 + tid; i < BB * 300; i += 64 * 256) {
    float v = ws[WS_Y1 + i];
    s += v; ss += v * v;
  }
  for (int o = 32; o; o >>= 1) { s += __shfl_xor(s, o); ss += __shfl_xor(ss, o); }
  __shared__ float sh[2][4];
  int wave = tid >> 6, lane = tid & 63;
  if (!lane) { sh[0][wave] = s; sh[1][wave] = ss; }
  __syncthreads();
  if (!tid) {
    float S = 0.f, SS2 = 0.f;
    for (int w = 0; w < 4; ++w) { S += sh[0][w]; SS2 += sh[1][w]; }
    ws[WS_PART2 + bid * 2] = S;
    ws[WS_PART2 + bid * 2 + 1] = SS2;
  }
}

// ---------------- k7: bn2 finalize + consts (inline) + out ----------------
__global__ void k7(const float* __restrict__ g2, const float* __restrict__ b2,
                   float* __restrict__ out, const float* __restrict__ ws) {
  __shared__ float Gs[2400];
  __shared__ float sh[4];   // a2, b2s, c0, c1
  int tid = threadIdx.x;    // 64
  for (int i = tid; i < 2400; i += 64) Gs[i] = ws[WS_G + i];
  {
    float s = ws[WS_PART2 + tid * 2], ss = ws[WS_PART2 + tid * 2 + 1];
    for (int o = 32; o; o >>= 1) { s += __shfl_xor(s, o); ss += __shfl_xor(ss, o); }
    if (!tid) {
      float n = (float)(BB * 300);
      float mean = s / n, var = ss / n - mean * mean;
      float a = (1.f / sqrtf(var + 1e-5f)) * g2[0];
      sh[0] = a; sh[1] = b2[0] - a * mean;
    }
  }
  __syncthreads();
  if (tid < 2) {
    int c = tid;
    float sg1 = 0.f, sg2 = 0.f, sg3 = 0.f;
    for (int k = 0; k < 300; ++k) sg1 += Gs[k * 2 + c];
    for (int k = 300; k < 900; ++k) sg2 += Gs[k * 2 + c];
    for (int j = 0; j < 300; ++j) sg3 += ws[WS_CLS + j] * Gs[(900 + j) * 2 + c];
    sh[2 + c] = ws[WS_CST0 + c] + sg3 + sh[1] * sg1 + ws[WS_STATS + 1] * sg2;
  }
  __syncthreads();
  int b = blockIdx.x * 64 + tid;
  float a1 = ws[WS_STATS + 0], a2 = sh[0];
  float c0 = sh[2], c1 = sh[3];
  const float* y1 = ws + WS_Y1 + b * 300;
  const float* ms = ws + WS_MSA + b * 600;
  float o0 = 0.f, o1 = 0.f;
  for (int k = 0; k < 300; ++k) { float v = y1[k]; o0 += v * Gs[k * 2]; o1 += v * Gs[k * 2 + 1]; }
  float p0 = 0.f, p1 = 0.f;
  for (int j = 0; j < 600; ++j) { float v = ms[j]; p0 += v * Gs[(300 + j) * 2]; p1 += v * Gs[(300 + j) * 2 + 1]; }
  out[b * 2] = a2 * o0 + a1 * p0 + c0;
  out[b * 2 + 1] = a2 * o1 + a1 * p1 + c1;
}

extern "C" void kernel_launch(void* const* d_in, const int* in_sizes, int n_in,
                              void* d_out, int out_size, void* d_ws, size_t ws_size,
                              hipStream_t stream) {
  const float* x    = (const float*)d_in[0];
  const float* Wp   = (const float*)d_in[1];
  const float* bp   = (const float*)d_in[2];
  const float* pos  = (const float*)d_in[3];
  const float* cle  = (const float*)d_in[4];
  const float* Wq   = (const float*)d_in[5];
  const float* Wk   = (const float*)d_in[6];
  const float* Wv   = (const float*)d_in[7];
  const float* bn1g = (const float*)d_in[8];
  const float* bn1b = (const float*)d_in[9];
  const float* Wp1  = (const float*)d_in[10];
  const float* bp1  = (const float*)d_in[11];
  const float* bn2g = (const float*)d_in[12];
  const float* bn2b = (const float*)d_in[13];
  const float* f1W  = (const float*)d_in[14];
  const float* f1b  = (const float*)d_in[15];
  const float* f2W  = (const float*)d_in[16];
  const float* f2b  = (const float*)d_in[17];
  float* ws = (float*)d_ws;
  float* out = (float*)d_out;

  hipLaunchKernelGGL(kC1, dim3(29), dim3(256), 0, stream, pos, cle, Wq, Wp1, f1W, f2W, f1b, f2b, ws);
  hipLaunchKernelGGL(kC2, dim3(150), dim3(256), 0, stream, Wk, ws);
  hipLaunchKernelGGL(kC3, dim3(52), dim3(256), 0, stream, pos, bp1, ws);
  hipLaunchKernelGGL(kA, dim3(512), dim3(512), 0, stream, x, Wp, bp, pos, Wv, ws);
  hipLaunchKernelGGL(k4a, dim3(64), dim3(256), 0, stream, ws);
  hipLaunchKernelGGL(k5, dim3(256), dim3(256), 0, stream, Wp1, bn1g, bn1b, ws);
  hipLaunchKernelGGL(k6a, dim3(64), dim3(256), 0, stream, ws);
  hipLaunchKernelGGL(k7, dim3(8), dim3(64), 0, stream, bn2g, bn2b, out, ws);
}

// Round 8
// 192.120 us; speedup vs baseline: 1.3509x; 1.3509x over previous
//
#include <hip/hip_runtime.h>
#include <hip/hip_fp16.h>
#include <math.h>

#define BB 512
#define SS 100
#define DE 150
#define DM 300   // 2*D_E (also == D_IN)
#define LL 101
#define NH 2

typedef _Float16 f16x8 __attribute__((ext_vector_type(8)));
typedef float f32x4 __attribute__((ext_vector_type(4)));

// ---- ws layout (float offsets) ----
#define WS_CLS    0        // [300]
#define WS_QK     320      // [2][300]
#define WS_S0     960      // [2]
#define WS_CPOS   964      // [100][2]
#define WS_CVEC   1200     // [300]
#define WS_COLSUM 1536     // [300]
#define WS_CST0   1856     // [2]
#define WS_STATS  1860     // [0]=a1 [1]=beta1
#define WS_PART1  1920     // [64][2]
#define WS_PART2  2048     // [64][2]
#define WS_G      2176     // [1200][2]
#define WS_Q0     4608     // [2][300]
#define WS_P3     5248     // [15][2][300]
#define WS_MSA    14336                     // [512][600]
#define WS_Y1     (WS_MSA + 512*600)        // [512][300]

// ---------------- kC1: q0 | Wp1 partials | cls | G=fc1@fc2 ----------------
__global__ void kC1(const float* __restrict__ pos, const float* __restrict__ cle,
                    const float* __restrict__ Wq, const float* __restrict__ Wp1,
                    const float* __restrict__ f1W, const float* __restrict__ f2W,
                    const float* __restrict__ f1b, const float* __restrict__ f2b,
                    float* __restrict__ ws) {
  __shared__ float cls[DM];
  int b = blockIdx.x, tid = threadIdx.x;
  if (b < 18) {
    for (int i = tid; i < DM; i += 256) cls[i] = (i < DE) ? cle[i] : pos[i - DE];
    __syncthreads();
  }
  if (b < 3) {
    int idx = b * 256 + tid;
    if (idx < NH * DM) {
      int h = idx / DM, e = idx % DM;
      const float* w = Wq + h * DM * DM + e;
      float acc = 0.f;
      for (int d = 0; d < DM; ++d) acc += cls[d] * w[d * DM];
      ws[WS_Q0 + idx] = acc;
    }
  } else if (b < 18) {
    int kb = b - 3;
    for (int n = tid; n < DM; n += 256) {
      float cs = 0.f, cv = 0.f;
      for (int k = kb * 60; k < kb * 60 + 60; ++k) {
        float w = Wp1[k * 300 + n];
        if (k < 600) cs += w; else cv += cls[k - 600] * w;
      }
      ws[WS_P3 + kb * 600 + n] = cs;
      ws[WS_P3 + kb * 600 + 300 + n] = cv;
    }
  } else if (b == 18) {
    for (int i = tid; i < DM; i += 256)
      ws[WS_CLS + i] = (i < DE) ? cle[i] : pos[i - DE];
  } else {
    int t = (b - 19) * 256 + tid;
    if (t < 2400) {
      int k = t >> 1, c = t & 1;
      const float* r = f1W + k * 512;
      float acc = 0.f;
      for (int m = 0; m < 512; ++m) acc += r[m] * f2W[m * 2 + c];
      ws[WS_G + t] = acc;
    } else if (t < 2402) {
      int c = t - 2400;
      float acc = f2b[c];
      for (int m = 0; m < 512; ++m) acc += f1b[m] * f2W[m * 2 + c];
      ws[WS_CST0 + c] = acc;
    }
  }
}

// ---------------- kC2: qk[h][d] = Wk[h][d][:] . q0[h][:] (wave per output) ----------------
__global__ void kC2(const float* __restrict__ Wk, float* __restrict__ ws) {
  __shared__ float q0s[NH * DM];
  int tid = threadIdx.x;
  for (int i = tid; i < NH * DM; i += 256) q0s[i] = ws[WS_Q0 + i];
  __syncthreads();
  int wave = tid >> 6, lane = tid & 63;
  int idx = blockIdx.x * 4 + wave;            // < 600
  int h = idx / DM, d = idx % DM;
  const float* w = Wk + h * DM * DM + d * DM;
  const float* q = q0s + h * DM;
  float acc = 0.f;
  for (int e = lane; e < DM; e += 64) acc += w[e] * q[e];
  for (int o = 32; o; o >>= 1) acc += __shfl_xor(acc, o);
  if (!lane) ws[WS_QK + idx] = acc;
}

// ---------------- kC3: cpos | s0 | combine(colsum,cvec) ----------------
__global__ void kC3(const float* __restrict__ pos, const float* __restrict__ bp1,
                    float* __restrict__ ws) {
  int b = blockIdx.x, tid = threadIdx.x;
  int wave = tid >> 6, lane = tid & 63;
  if (b < 50) {
    int idx = b * 4 + wave;                   // < 200, = tt*2+h
    int tt = idx >> 1, h = idx & 1;
    const float* pr = pos + (tt + 1) * DE;
    const float* qk = ws + WS_QK + h * DM + DE;
    float acc = 0.f;
    for (int j = lane; j < DE; j += 64) acc += pr[j] * qk[j];
    for (int o = 32; o; o >>= 1) acc += __shfl_xor(acc, o);
    if (!lane) ws[WS_CPOS + idx] = acc;
  } else if (b == 50) {
    if (wave < NH) {
      float acc = 0.f;
      for (int d = lane; d < DM; d += 64) acc += ws[WS_CLS + d] * ws[WS_QK + wave * DM + d];
      for (int o = 32; o; o >>= 1) acc += __shfl_xor(acc, o);
      if (!lane) ws[WS_S0 + wave] = acc;
    }
  } else {
    for (int n = tid; n < DM; n += 256) {
      float cs = 0.f, cv = bp1[n];
      for (int p = 0; p < 15; ++p) {
        cs += ws[WS_P3 + p * 600 + n];
        cv += ws[WS_P3 + p * 600 + 300 + n];
      }
      ws[WS_COLSUM + n] = cs;
      ws[WS_CVEC + n] = cv;
    }
  }
}

// ---------------- kA: MFMA h-GEMM -> scores -> softmax -> zbar -> msa ----------------
// 512 threads = 8 waves (2M x 4N). M padded to 128, N tiles {0-2},{3-5},{6-8},{9}.
// A (x) direct from global as fp16 fragments; B (Wp) double-buffered fp16 in LDS,
// layout [kq8][n][8] so fragment read = one aligned ds_read_b128.
// LDS: hb 30,400 + wpt 20,480 + aux 5,120 + zb 2,400 = 58,400 B.
__launch_bounds__(512, 4)
__global__ void kA(const float* __restrict__ x, const float* __restrict__ Wp,
                   const float* __restrict__ bp, const float* __restrict__ pos,
                   const float* __restrict__ Wv, float* __restrict__ ws) {
  __shared__ __half hb[SS][DE + 2];
  __shared__ __align__(16) _Float16 wpt[2][5120];   // [kq8][n][8] halves per buffer
  __shared__ float aux[1280];
  __shared__ float zb[NH * DM];
  int b = blockIdx.x, tid = threadIdx.x;
  int w = tid >> 6, lane = tid & 63;
  int l16 = lane & 15, lg = lane >> 4;
  int wm = w >> 2, wn = w & 3;
  int nnt = (wn < 3) ? 3 : 1;
  int nt0 = (wn < 3) ? wn * 3 : 9;

  const float* xb = x + b * (SS * DM);
  int rowg[4];
#pragma unroll
  for (int mt = 0; mt < 4; ++mt) {
    int r = wm * 64 + mt * 16 + l16;
    rowg[mt] = (r < SS) ? r : (SS - 1);
  }

  f32x4 acc[4][3];
#pragma unroll
  for (int mt = 0; mt < 4; ++mt)
#pragma unroll
    for (int nti = 0; nti < 3; ++nti) acc[mt][nti] = (f32x4){0.f, 0.f, 0.f, 0.f};

  // ---- stage K-step 0 into buf 0 ----
  for (int task = tid; task < 640; task += 512) {
    int kq8 = task / 160, n = task % 160;
    int kbase = kq8 * 8;
    f16x8 pk;
#pragma unroll
    for (int j = 0; j < 8; ++j) {
      float v = (n < DE) ? Wp[(kbase + j) * DE + n] : 0.f;
      pk[j] = (_Float16)v;
    }
    *(f16x8*)&wpt[0][task * 8] = pk;
  }
  __syncthreads();

  // ---- K loop: 10 steps of 32 ----
  for (int s = 0; s < 10; ++s) {
    int bi = s & 1;
    // 1. issue next-step stage loads (global -> regs), latency hides under MFMA
    float sreg[2][8];
    int ntask[2] = {-1, -1};
    if (s < 9) {
      int ti = 0;
      for (int task = tid; task < 640; task += 512, ++ti) {
        int kq8 = task / 160, n = task % 160;
        int kbase = (s + 1) * 32 + kq8 * 8;
        ntask[ti] = task;
#pragma unroll
        for (int j = 0; j < 8; ++j) {
          int k = kbase + j;
          sreg[ti][j] = (k < DM && n < DE) ? Wp[k * DE + n] : 0.f;
        }
      }
    }
    // 2. compute from buf[bi]
    f16x8 Bf[3];
#pragma unroll
    for (int nti = 0; nti < 3; ++nti) {
      if (nti < nnt) {
        int task = lg * 160 + (nt0 + nti) * 16 + l16;
        Bf[nti] = *(const f16x8*)&wpt[bi][task * 8];
      }
    }
    int k0 = s * 32 + lg * 8;
#pragma unroll
    for (int mt = 0; mt < 4; ++mt) {
      const float* xr = xb + rowg[mt] * DM;
      f16x8 Af;
      if (k0 + 8 <= DM) {
        float4 q0 = *(const float4*)(xr + k0);
        float4 q1 = *(const float4*)(xr + k0 + 4);
        Af[0] = (_Float16)q0.x; Af[1] = (_Float16)q0.y;
        Af[2] = (_Float16)q0.z; Af[3] = (_Float16)q0.w;
        Af[4] = (_Float16)q1.x; Af[5] = (_Float16)q1.y;
        Af[6] = (_Float16)q1.z; Af[7] = (_Float16)q1.w;
      } else {
#pragma unroll
        for (int j = 0; j < 8; ++j) {
          int k = k0 + j;
          Af[j] = (k < DM) ? (_Float16)xr[k] : (_Float16)0.f;
        }
      }
#pragma unroll
      for (int nti = 0; nti < 3; ++nti)
        if (nti < nnt)
          acc[mt][nti] = __builtin_amdgcn_mfma_f32_16x16x32_f16(Af, Bf[nti], acc[mt][nti], 0, 0, 0);
    }
    // 3. write staged regs to buf[bi^1]
    if (s < 9) {
#pragma unroll
      for (int ti = 0; ti < 2; ++ti) {
        if (ntask[ti] >= 0) {
          f16x8 pk;
#pragma unroll
          for (int j = 0; j < 8; ++j) pk[j] = (_Float16)sreg[ti][j];
          *(f16x8*)&wpt[bi ^ 1][ntask[ti] * 8] = pk;
        }
      }
    }
    __syncthreads();
  }

  // ---- write hb = relu(acc + bp) in fp16 ----
#pragma unroll
  for (int nti = 0; nti < 3; ++nti) {
    if (nti < nnt) {
      int col = (nt0 + nti) * 16 + l16;
      float bpv = (col < DE) ? bp[col] : 0.f;
#pragma unroll
      for (int mt = 0; mt < 4; ++mt) {
        int rbase = wm * 64 + mt * 16 + lg * 4;
        f32x4 v = acc[mt][nti];
#pragma unroll
        for (int reg = 0; reg < 4; ++reg) {
          int row = rbase + reg;
          if (row < SS && col < DE) {
            float hv = v[reg] + bpv;
            hb[row][col] = __float2half(hv > 0.f ? hv : 0.f);
          }
        }
      }
    }
  }
  // reload aux: qk first-halves + cls
  for (int i = tid; i < DM; i += 512) {
    aux[i] = ws[WS_QK + (i / DE) * DM + (i % DE)];
    aux[DM + i] = ws[WS_CLS + i];
  }
  __syncthreads();

  // ---- phase 2: scores ----
  if (tid < NH * SS) {
    int hh = tid / SS, tt = tid % SS;
    float s = 0.f;
    for (int j = 0; j < DE; ++j) s += __half2float(hb[tt][j]) * aux[hh * DE + j];
    aux[600 + hh * LL + tt + 1] = s + ws[WS_CPOS + tt * NH + hh];
  } else if (tid < NH * SS + NH) {
    int hh = tid - NH * SS;
    aux[600 + hh * LL] = ws[WS_S0 + hh];
  }
  __syncthreads();

  // ---- phase 3: softmax (one wave per head) ----
  if (w < NH) {
    float v0 = aux[600 + w * LL + lane];
    float v1 = (lane + 64 < LL) ? aux[600 + w * LL + lane + 64] : -1e30f;
    float m = fmaxf(v0, v1);
    for (int o = 32; o; o >>= 1) m = fmaxf(m, __shfl_xor(m, o));
    float e0 = expf(v0 - m);
    float e1 = (lane + 64 < LL) ? expf(v1 - m) : 0.f;
    float s = e0 + e1;
    for (int o = 32; o; o >>= 1) s += __shfl_xor(s, o);
    float inv = 1.f / s;
    aux[802 + w * LL + lane] = e0 * inv;
    if (lane + 64 < LL) aux[802 + w * LL + lane + 64] = e1 * inv;
  }
  __syncthreads();

  // ---- phase 4: zbar[h][d] = sum_t p[t]*z[b,t,d]  (into LDS) ----
  for (int o = tid; o < NH * DM; o += 512) {
    int hh = o / DM, d = o % DM;
    const float* p = &aux[802 + hh * LL];
    float acc2 = p[0] * aux[DM + d];
    if (d < DE) {
      for (int t = 1; t <= SS; ++t) acc2 += p[t] * __half2float(hb[t - 1][d]);
    } else {
      int dd = d - DE;
      for (int t = 1; t <= SS; ++t) acc2 += p[t] * pos[t * DE + dd];
    }
    zb[o] = acc2;
  }
  __syncthreads();

  // ---- phase 5: msa[b] = zb @ Wv (per head) ----
  for (int e = tid; e < NH * DM; e += 512) {
    int hh = e / DM, ee = e % DM;
    const float* wv = Wv + hh * DM * DM + ee;
    const float* z = zb + hh * DM;
    float s0 = 0.f, s1 = 0.f;
    for (int d = 0; d < DM; d += 2) {
      s0 += z[d] * wv[d * DM];
      s1 += z[d + 1] * wv[(d + 1) * DM];
    }
    ws[WS_MSA + b * 600 + e] = s0 + s1;
  }
}

// ---------------- k4a: bn1 channel-0 partial stats ----------------
__global__ void k4a(float* __restrict__ ws) {
  int tid = threadIdx.x, bid = blockIdx.x;
  float s = 0.f, ss = 0.f;
  for (int i = bid * 256 + tid; i < BB * 600; i += 64 * 256) {
    float v = ws[WS_MSA + i];
    s += v; ss += v * v;
  }
  for (int o = 32; o; o >>= 1) { s += __shfl_xor(s, o); ss += __shfl_xor(ss, o); }
  __shared__ float sh[2][4];
  int wave = tid >> 6, lane = tid & 63;
  if (!lane) { sh[0][wave] = s; sh[1][wave] = ss; }
  __syncthreads();
  if (!tid) {
    float S = 0.f, SS2 = 0.f;
    for (int w = 0; w < 4; ++w) { S += sh[0][w]; SS2 += sh[1][w]; }
    ws[WS_PART1 + bid * 2] = S;
    ws[WS_PART1 + bid * 2 + 1] = SS2;
  }
}

// ---------------- k5: bn1 finalize (inline) + y1 = relu(a1*(msa@Wp1[:600]) + ...) ----------------
__launch_bounds__(256)
__global__ void k5(const float* __restrict__ Wp1, const float* __restrict__ g1,
                   const float* __restrict__ b1, float* __restrict__ ws) {
  __shared__ float ab[2][600];
  __shared__ float s_a1, s_b1;
  int b0 = blockIdx.x * 2, tid = threadIdx.x;
  for (int i = tid; i < 2 * 600; i += 256) ab[i / 600][i % 600] = ws[WS_MSA + b0 * 600 + i];
  if (tid < 64) {
    float s = ws[WS_PART1 + tid * 2], ss = ws[WS_PART1 + tid * 2 + 1];
    for (int o = 32; o; o >>= 1) { s += __shfl_xor(s, o); ss += __shfl_xor(ss, o); }
    if (!tid) {
      float n = (float)(BB * 600);
      float mean = s / n, var = ss / n - mean * mean;
      float a = (1.f / sqrtf(var + 1e-5f)) * g1[0];
      s_a1 = a; s_b1 = b1[0] - a * mean;
      if (blockIdx.x == 0) { ws[WS_STATS + 0] = a; ws[WS_STATS + 1] = s_b1; }
    }
  }
  __syncthreads();
  float a1 = s_a1, beta1 = s_b1;
  for (int n = tid; n < DM; n += 256) {
    float acc0 = 0.f, acc1 = 0.f;
    for (int k = 0; k < 600; ++k) {
      float w = Wp1[k * 300 + n];
      acc0 += ab[0][k] * w;
      acc1 += ab[1][k] * w;
    }
    float c = beta1 * ws[WS_COLSUM + n] + ws[WS_CVEC + n];
    float v0 = a1 * acc0 + c, v1 = a1 * acc1 + c;
    ws[WS_Y1 + b0 * 300 + n] = v0 > 0.f ? v0 : 0.f;
    ws[WS_Y1 + (b0 + 1) * 300 + n] = v1 > 0.f ? v1 : 0.f;
  }
}

// ---------------- k6a: bn2 channel-0 partial stats ----------------
__global__ void k6a(float* __restrict__ ws) {
  int tid = threadIdx.x, bid = blockIdx.x;
  float s = 0.f, ss = 0.f;
  for (int i = bid * 256 + tid; i < BB * 300; i += 64 * 256) {
    float v = ws[WS_Y1 + i];
    s += v; ss += v * v;
  }
  for (int o = 32; o; o >>= 1) { s += __shfl_xor(s, o); ss += __shfl_xor(ss, o); }
  __shared__ float sh[2][4];
  int wave = tid >> 6, lane = tid & 63;
  if (!lane) { sh[0][wave] = s; sh[1][wave] = ss; }
  __syncthreads();
  if (!tid) {
    float S = 0.f, SS2 = 0.f;
    for (int w = 0; w < 4; ++w) { S += sh[0][w]; SS2 += sh[1][w]; }
    ws[WS_PART2 + bid * 2] = S;
    ws[WS_PART2 + bid * 2 + 1] = SS2;
  }
}

// ---------------- k7: bn2 finalize + consts (inline) + out ----------------
__global__ void k7(const float* __restrict__ g2, const float* __restrict__ b2,
                   float* __restrict__ out, const float* __restrict__ ws) {
  __shared__ float Gs[2400];
  __shared__ float sh[4];   // a2, b2s, c0, c1
  int tid = threadIdx.x;    // 64
  for (int i = tid; i < 2400; i += 64) Gs[i] = ws[WS_G + i];
  {
    float s = ws[WS_PART2 + tid * 2], ss = ws[WS_PART2 + tid * 2 + 1];
    for (int o = 32; o; o >>= 1) { s += __shfl_xor(s, o); ss += __shfl_xor(ss, o); }
    if (!tid) {
      float n = (float)(BB * 300);
      float mean = s / n, var = ss / n - mean * mean;
      float a = (1.f / sqrtf(var + 1e-5f)) * g2[0];
      sh[0] = a; sh[1] = b2[0] - a * mean;
    }
  }
  __syncthreads();
  if (tid < 2) {
    int c = tid;
    float sg1 = 0.f, sg2 = 0.f, sg3 = 0.f;
    for (int k = 0; k < 300; ++k) sg1 += Gs[k * 2 + c];
    for (int k = 300; k < 900; ++k) sg2 += Gs[k * 2 + c];
    for (int j = 0; j < 300; ++j) sg3 += ws[WS_CLS + j] * Gs[(900 + j) * 2 + c];
    sh[2 + c] = ws[WS_CST0 + c] + sg3 + sh[1] * sg1 + ws[WS_STATS + 1] * sg2;
  }
  __syncthreads();
  int b = blockIdx.x * 64 + tid;
  float a1 = ws[WS_STATS + 0], a2 = sh[0];
  float c0 = sh[2], c1 = sh[3];
  const float* y1 = ws + WS_Y1 + b * 300;
  const float* ms = ws + WS_MSA + b * 600;
  float o0 = 0.f, o1 = 0.f;
  for (int k = 0; k < 300; ++k) { float v = y1[k]; o0 += v * Gs[k * 2]; o1 += v * Gs[k * 2 + 1]; }
  float p0 = 0.f, p1 = 0.f;
  for (int j = 0; j < 600; ++j) { float v = ms[j]; p0 += v * Gs[(300 + j) * 2]; p1 += v * Gs[(300 + j) * 2 + 1]; }
  out[b * 2] = a2 * o0 + a1 * p0 + c0;
  out[b * 2 + 1] = a2 * o1 + a1 * p1 + c1;
}

extern "C" void kernel_launch(void* const* d_in, const int* in_sizes, int n_in,
                              void* d_out, int out_size, void* d_ws, size_t ws_size,
                              hipStream_t stream) {
  const float* x    = (const float*)d_in[0];
  const float* Wp   = (const float*)d_in[1];
  const float* bp   = (const float*)d_in[2];
  const float* pos  = (const float*)d_in[3];
  const float* cle  = (const float*)d_in[4];
  const float* Wq   = (const float*)d_in[5];
  const float* Wk   = (const float*)d_in[6];
  const float* Wv   = (const float*)d_in[7];
  const float* bn1g = (const float*)d_in[8];
  const float* bn1b = (const float*)d_in[9];
  const float* Wp1  = (const float*)d_in[10];
  const float* bp1  = (const float*)d_in[11];
  const float* bn2g = (const float*)d_in[12];
  const float* bn2b = (const float*)d_in[13];
  const float* f1W  = (const float*)d_in[14];
  const float* f1b  = (const float*)d_in[15];
  const float* f2W  = (const float*)d_in[16];
  const float* f2b  = (const float*)d_in[17];
  float* ws = (float*)d_ws;
  float* out = (float*)d_out;

  hipLaunchKernelGGL(kC1, dim3(29), dim3(256), 0, stream, pos, cle, Wq, Wp1, f1W, f2W, f1b, f2b, ws);
  hipLaunchKernelGGL(kC2, dim3(150), dim3(256), 0, stream, Wk, ws);
  hipLaunchKernelGGL(kC3, dim3(52), dim3(256), 0, stream, pos, bp1, ws);
  hipLaunchKernelGGL(kA, dim3(512), dim3(512), 0, stream, x, Wp, bp, pos, Wv, ws);
  hipLaunchKernelGGL(k4a, dim3(64), dim3(256), 0, stream, ws);
  hipLaunchKernelGGL(k5, dim3(256), dim3(256), 0, stream, Wp1, bn1g, bn1b, ws);
  hipLaunchKernelGGL(k6a, dim3(64), dim3(256), 0, stream, ws);
  hipLaunchKernelGGL(k7, dim3(8), dim3(64), 0, stream, bn2g, bn2b, out, ws);
}

// Round 9
// 172.542 us; speedup vs baseline: 1.5042x; 1.1135x over previous
//
#include <hip/hip_runtime.h>
#include <hip/hip_fp16.h>
#include <math.h>

#define BB 512
#define SS 100
#define DE 150
#define DM 300   // 2*D_E (also == D_IN)
#define LL 101
#define NH 2

typedef _Float16 f16x8 __attribute__((ext_vector_type(8)));
typedef float f32x4 __attribute__((ext_vector_type(4)));

// ---- ws layout (float offsets) ----
#define WS_CLS    0        // [300]
#define WS_QK     320      // [2][300]
#define WS_S0     960      // [2]
#define WS_CPOS   964      // [100][2]
#define WS_CVEC   1200     // [300]
#define WS_COLSUM 1536     // [300]
#define WS_CST0   1856     // [2]
#define WS_STATS  1860     // [0]=a1 [1]=beta1
#define WS_PART1  1920     // [64][2]
#define WS_PART2  2048     // [64][2]
#define WS_G      2176     // [1200][2]
#define WS_Q0     4608     // [2][300]
#define WS_P3     5248     // [15][2][300]
#define WS_MSA    14336                     // [512][600]
#define WS_Y1     (WS_MSA + 512*600)        // [512][300]

// ---------------- kC1: q0 | Wp1 partials | cls | G=fc1@fc2 ----------------
__global__ void kC1(const float* __restrict__ pos, const float* __restrict__ cle,
                    const float* __restrict__ Wq, const float* __restrict__ Wp1,
                    const float* __restrict__ f1W, const float* __restrict__ f2W,
                    const float* __restrict__ f1b, const float* __restrict__ f2b,
                    float* __restrict__ ws) {
  __shared__ float cls[DM];
  int b = blockIdx.x, tid = threadIdx.x;
  if (b < 18) {
    for (int i = tid; i < DM; i += 256) cls[i] = (i < DE) ? cle[i] : pos[i - DE];
    __syncthreads();
  }
  if (b < 3) {
    int idx = b * 256 + tid;
    if (idx < NH * DM) {
      int h = idx / DM, e = idx % DM;
      const float* w = Wq + h * DM * DM + e;
      float acc = 0.f;
      for (int d = 0; d < DM; ++d) acc += cls[d] * w[d * DM];
      ws[WS_Q0 + idx] = acc;
    }
  } else if (b < 18) {
    int kb = b - 3;
    for (int n = tid; n < DM; n += 256) {
      float cs = 0.f, cv = 0.f;
      for (int k = kb * 60; k < kb * 60 + 60; ++k) {
        float w = Wp1[k * 300 + n];
        if (k < 600) cs += w; else cv += cls[k - 600] * w;
      }
      ws[WS_P3 + kb * 600 + n] = cs;
      ws[WS_P3 + kb * 600 + 300 + n] = cv;
    }
  } else if (b == 18) {
    for (int i = tid; i < DM; i += 256)
      ws[WS_CLS + i] = (i < DE) ? cle[i] : pos[i - DE];
  } else {
    int t = (b - 19) * 256 + tid;
    if (t < 2400) {
      int k = t >> 1, c = t & 1;
      const float* r = f1W + k * 512;
      float acc = 0.f;
      for (int m = 0; m < 512; ++m) acc += r[m] * f2W[m * 2 + c];
      ws[WS_G + t] = acc;
    } else if (t < 2402) {
      int c = t - 2400;
      float acc = f2b[c];
      for (int m = 0; m < 512; ++m) acc += f1b[m] * f2W[m * 2 + c];
      ws[WS_CST0 + c] = acc;
    }
  }
}

// ---------------- kC2: qk[h][d] = Wk[h][d][:] . q0[h][:] (wave per output) ----------------
__global__ void kC2(const float* __restrict__ Wk, float* __restrict__ ws) {
  __shared__ float q0s[NH * DM];
  int tid = threadIdx.x;
  for (int i = tid; i < NH * DM; i += 256) q0s[i] = ws[WS_Q0 + i];
  __syncthreads();
  int wave = tid >> 6, lane = tid & 63;
  int idx = blockIdx.x * 4 + wave;            // < 600
  int h = idx / DM, d = idx % DM;
  const float* w = Wk + h * DM * DM + d * DM;
  const float* q = q0s + h * DM;
  float acc = 0.f;
  for (int e = lane; e < DM; e += 64) acc += w[e] * q[e];
  for (int o = 32; o; o >>= 1) acc += __shfl_xor(acc, o);
  if (!lane) ws[WS_QK + idx] = acc;
}

// ---------------- kC3: cpos | s0 | combine(colsum,cvec) ----------------
__global__ void kC3(const float* __restrict__ pos, const float* __restrict__ bp1,
                    float* __restrict__ ws) {
  int b = blockIdx.x, tid = threadIdx.x;
  int wave = tid >> 6, lane = tid & 63;
  if (b < 50) {
    int idx = b * 4 + wave;                   // < 200, = tt*2+h
    int tt = idx >> 1, h = idx & 1;
    const float* pr = pos + (tt + 1) * DE;
    const float* qk = ws + WS_QK + h * DM + DE;
    float acc = 0.f;
    for (int j = lane; j < DE; j += 64) acc += pr[j] * qk[j];
    for (int o = 32; o; o >>= 1) acc += __shfl_xor(acc, o);
    if (!lane) ws[WS_CPOS + idx] = acc;
  } else if (b == 50) {
    if (wave < NH) {
      float acc = 0.f;
      for (int d = lane; d < DM; d += 64) acc += ws[WS_CLS + d] * ws[WS_QK + wave * DM + d];
      for (int o = 32; o; o >>= 1) acc += __shfl_xor(acc, o);
      if (!lane) ws[WS_S0 + wave] = acc;
    }
  } else {
    for (int n = tid; n < DM; n += 256) {
      float cs = 0.f, cv = bp1[n];
      for (int p = 0; p < 15; ++p) {
        cs += ws[WS_P3 + p * 600 + n];
        cv += ws[WS_P3 + p * 600 + 300 + n];
      }
      ws[WS_COLSUM + n] = cs;
      ws[WS_CVEC + n] = cv;
    }
  }
}

// ---------------- kA: MFMA h-GEMM (x staged in LDS) -> scores -> softmax -> zbar -> msa ----
// 512 threads = 8 waves (2M x 4N). A (x) staged fp16 in LDS xs[100][40] (pad-40 rows:
// b128 fragment reads are 2-way bank aliased = free). B (Wp) fp16 in wpt[kq8][160][8].
// Single-buffered, register-prefetch (issue s+1 globals before s MFMAs), 2 barriers/step.
// LDS: hb 30,400 + wpt 10,240 + xs 8,000 + aux 5,120 + zb 2,400 = 56,160 B.
__launch_bounds__(512, 4)
__global__ void kA(const float* __restrict__ x, const float* __restrict__ Wp,
                   const float* __restrict__ bp, const float* __restrict__ pos,
                   const float* __restrict__ Wv, float* __restrict__ ws) {
  __shared__ __half hb[SS][DE + 2];
  __shared__ __align__(16) _Float16 wpt[4 * 160 * 8];   // [kq8][n][8]
  __shared__ __align__(16) _Float16 xs[SS * 40];        // [r][40] (32 cols + pad)
  __shared__ float aux[1280];
  __shared__ float zb[NH * DM];
  int b = blockIdx.x, tid = threadIdx.x;
  int w = tid >> 6, lane = tid & 63;
  int l16 = lane & 15, lg = lane >> 4;
  int wm = w >> 2, wn = w & 3;
  int nnt = (wn < 3) ? 3 : 1;
  int nt0 = (wn < 3) ? wn * 3 : 9;

  const float* xb = x + b * (SS * DM);
  int rowl[4];
#pragma unroll
  for (int mt = 0; mt < 4; ++mt) {
    int r = wm * 64 + mt * 16 + l16;
    rowl[mt] = (r < SS) ? r : (SS - 1);
  }

  f32x4 acc[4][3];
#pragma unroll
  for (int mt = 0; mt < 4; ++mt)
#pragma unroll
    for (int nti = 0; nti < 3; ++nti) acc[mt][nti] = (f32x4){0.f, 0.f, 0.f, 0.f};

  float xr[4][2];   // x prefetch: 1600 float2 tasks / 512 threads
  float wr[2][8];   // Wp prefetch: 640 tasks / 512 threads

#define STAGE_LOAD(S)                                                          \
  {                                                                            \
    int kc_ = (S) * 32;                                                        \
    _Pragma("unroll")                                                          \
    for (int i_ = 0; i_ < 4; ++i_) {                                           \
      int t_ = tid + 512 * i_;                                                 \
      if (t_ < 1600) {                                                         \
        int r_ = t_ >> 4, c_ = t_ & 15, k_ = kc_ + 2 * c_;                     \
        if (k_ + 1 < DM) {                                                     \
          float2 v_ = *(const float2*)(xb + r_ * DM + k_);                     \
          xr[i_][0] = v_.x; xr[i_][1] = v_.y;                                  \
        } else {                                                               \
          xr[i_][0] = (k_ < DM) ? xb[r_ * DM + k_] : 0.f;                      \
          xr[i_][1] = 0.f;                                                     \
        }                                                                      \
      }                                                                        \
    }                                                                          \
    _Pragma("unroll")                                                          \
    for (int i_ = 0; i_ < 2; ++i_) {                                           \
      int t_ = tid + 512 * i_;                                                 \
      if (t_ < 640) {                                                          \
        int kq_ = t_ / 160, n_ = t_ % 160;                                     \
        _Pragma("unroll")                                                      \
        for (int j_ = 0; j_ < 8; ++j_) {                                       \
          int k_ = kc_ + kq_ * 8 + j_;                                         \
          wr[i_][j_] = (k_ < DM && n_ < DE) ? Wp[k_ * DE + n_] : 0.f;          \
        }                                                                      \
      }                                                                        \
    }                                                                          \
  }

#define STAGE_WRITE()                                                          \
  {                                                                            \
    _Pragma("unroll")                                                          \
    for (int i_ = 0; i_ < 4; ++i_) {                                           \
      int t_ = tid + 512 * i_;                                                 \
      if (t_ < 1600) {                                                         \
        int r_ = t_ >> 4, c_ = t_ & 15;                                        \
        __half2 h_ = __floats2half2_rn(xr[i_][0], xr[i_][1]);                  \
        *(__half2*)&xs[r_ * 40 + 2 * c_] = h_;                                 \
      }                                                                        \
    }                                                                          \
    _Pragma("unroll")                                                          \
    for (int i_ = 0; i_ < 2; ++i_) {                                           \
      int t_ = tid + 512 * i_;                                                 \
      if (t_ < 640) {                                                          \
        f16x8 pk_;                                                             \
        _Pragma("unroll")                                                      \
        for (int j_ = 0; j_ < 8; ++j_) pk_[j_] = (_Float16)wr[i_][j_];         \
        *(f16x8*)&wpt[t_ * 8] = pk_;                                           \
      }                                                                        \
    }                                                                          \
  }

  // prologue: stage step 0
  STAGE_LOAD(0);
  STAGE_WRITE();
  __syncthreads();

  for (int s = 0; s < 10; ++s) {
    // 1. issue next-step global loads (latency hides under MFMA)
    if (s < 9) STAGE_LOAD(s + 1);
    // 2. compute from LDS
    f16x8 Bf[3];
#pragma unroll
    for (int nti = 0; nti < 3; ++nti)
      if (nti < nnt) {
        int n = (nt0 + nti) * 16 + l16;
        Bf[nti] = *(const f16x8*)&wpt[(lg * 160 + n) * 8];
      }
#pragma unroll
    for (int mt = 0; mt < 4; ++mt) {
      f16x8 Af = *(const f16x8*)&xs[rowl[mt] * 40 + lg * 8];
#pragma unroll
      for (int nti = 0; nti < 3; ++nti)
        if (nti < nnt)
          acc[mt][nti] = __builtin_amdgcn_mfma_f32_16x16x32_f16(Af, Bf[nti], acc[mt][nti], 0, 0, 0);
    }
    __syncthreads();   // everyone done reading xs/wpt
    // 3. write staged regs
    if (s < 9) {
      STAGE_WRITE();
    }
    __syncthreads();   // writes visible
  }

  // ---- write hb = relu(acc + bp) in fp16 ----
#pragma unroll
  for (int nti = 0; nti < 3; ++nti) {
    if (nti < nnt) {
      int col = (nt0 + nti) * 16 + l16;
      float bpv = (col < DE) ? bp[col] : 0.f;
#pragma unroll
      for (int mt = 0; mt < 4; ++mt) {
        int rbase = wm * 64 + mt * 16 + lg * 4;
        f32x4 v = acc[mt][nti];
#pragma unroll
        for (int reg = 0; reg < 4; ++reg) {
          int row = rbase + reg;
          if (row < SS && col < DE) {
            float hv = v[reg] + bpv;
            hb[row][col] = __float2half(hv > 0.f ? hv : 0.f);
          }
        }
      }
    }
  }
  // reload aux: qk first-halves + cls
  for (int i = tid; i < DM; i += 512) {
    aux[i] = ws[WS_QK + (i / DE) * DM + (i % DE)];
    aux[DM + i] = ws[WS_CLS + i];
  }
  __syncthreads();

  // ---- phase 2: scores (hb read as half2) ----
  if (tid < NH * SS) {
    int hh = tid / SS, tt = tid % SS;
    const __half2* hr = (const __half2*)&hb[tt][0];
    const float* qr = &aux[hh * DE];
    float s = 0.f;
    for (int j2 = 0; j2 < DE / 2; ++j2) {
      float2 hv = __half22float2(hr[j2]);
      float2 qv = *(const float2*)&qr[2 * j2];
      s += hv.x * qv.x + hv.y * qv.y;
    }
    aux[600 + hh * LL + tt + 1] = s + ws[WS_CPOS + tt * NH + hh];
  } else if (tid < NH * SS + NH) {
    int hh = tid - NH * SS;
    aux[600 + hh * LL] = ws[WS_S0 + hh];
  }
  __syncthreads();

  // ---- phase 3: softmax (one wave per head) ----
  if (w < NH) {
    float v0 = aux[600 + w * LL + lane];
    float v1 = (lane + 64 < LL) ? aux[600 + w * LL + lane + 64] : -1e30f;
    float m = fmaxf(v0, v1);
    for (int o = 32; o; o >>= 1) m = fmaxf(m, __shfl_xor(m, o));
    float e0 = expf(v0 - m);
    float e1 = (lane + 64 < LL) ? expf(v1 - m) : 0.f;
    float s = e0 + e1;
    for (int o = 32; o; o >>= 1) s += __shfl_xor(s, o);
    float inv = 1.f / s;
    aux[802 + w * LL + lane] = e0 * inv;
    if (lane + 64 < LL) aux[802 + w * LL + lane + 64] = e1 * inv;
  }
  __syncthreads();

  // ---- phase 4: zbar[h][d] = sum_t p[t]*z[b,t,d]  (into LDS) ----
  for (int o = tid; o < NH * DM; o += 512) {
    int hh = o / DM, d = o % DM;
    const float* p = &aux[802 + hh * LL];
    float acc2 = p[0] * aux[DM + d];
    if (d < DE) {
      for (int t = 1; t <= SS; ++t) acc2 += p[t] * __half2float(hb[t - 1][d]);
    } else {
      int dd = d - DE;
      for (int t = 1; t <= SS; ++t) acc2 += p[t] * pos[t * DE + dd];
    }
    zb[o] = acc2;
  }
  __syncthreads();

  // ---- phase 5: msa[b] = zb @ Wv (per head) ----
  for (int e = tid; e < NH * DM; e += 512) {
    int hh = e / DM, ee = e % DM;
    const float* wv = Wv + hh * DM * DM + ee;
    const float* z = zb + hh * DM;
    float s0 = 0.f, s1 = 0.f;
    for (int d = 0; d < DM; d += 2) {
      s0 += z[d] * wv[d * DM];
      s1 += z[d + 1] * wv[(d + 1) * DM];
    }
    ws[WS_MSA + b * 600 + e] = s0 + s1;
  }
}

// ---------------- k4a: bn1 channel-0 partial stats ----------------
__global__ void k4a(float* __restrict__ ws) {
  int tid = threadIdx.x, bid = blockIdx.x;
  float s = 0.f, ss = 0.f;
  for (int i = bid * 256 + tid; i < BB * 600; i += 64 * 256) {
    float v = ws[WS_MSA + i];
    s += v; ss += v * v;
  }
  for (int o = 32; o; o >>= 1) { s += __shfl_xor(s, o); ss += __shfl_xor(ss, o); }
  __shared__ float sh[2][4];
  int wave = tid >> 6, lane = tid & 63;
  if (!lane) { sh[0][wave] = s; sh[1][wave] = ss; }
  __syncthreads();
  if (!tid) {
    float S = 0.f, SS2 = 0.f;
    for (int w = 0; w < 4; ++w) { S += sh[0][w]; SS2 += sh[1][w]; }
    ws[WS_PART1 + bid * 2] = S;
    ws[WS_PART1 + bid * 2 + 1] = SS2;
  }
}

// ---------------- k5: bn1 finalize (inline) + y1 = relu(a1*(msa@Wp1[:600]) + ...) ----------------
__launch_bounds__(256)
__global__ void k5(const float* __restrict__ Wp1, const float* __restrict__ g1,
                   const float* __restrict__ b1, float* __restrict__ ws) {
  __shared__ float ab[2][600];
  __shared__ float s_a1, s_b1;
  int b0 = blockIdx.x * 2, tid = threadIdx.x;
  for (int i = tid; i < 2 * 600; i += 256) ab[i / 600][i % 600] = ws[WS_MSA + b0 * 600 + i];
  if (tid < 64) {
    float s = ws[WS_PART1 + tid * 2], ss = ws[WS_PART1 + tid * 2 + 1];
    for (int o = 32; o; o >>= 1) { s += __shfl_xor(s, o); ss += __shfl_xor(ss, o); }
    if (!tid) {
      float n = (float)(BB * 600);
      float mean = s / n, var = ss / n - mean * mean;
      float a = (1.f / sqrtf(var + 1e-5f)) * g1[0];
      s_a1 = a; s_b1 = b1[0] - a * mean;
      if (blockIdx.x == 0) { ws[WS_STATS + 0] = a; ws[WS_STATS + 1] = s_b1; }
    }
  }
  __syncthreads();
  float a1 = s_a1, beta1 = s_b1;
  for (int n = tid; n < DM; n += 256) {
    float acc0 = 0.f, acc1 = 0.f;
    for (int k = 0; k < 600; ++k) {
      float w = Wp1[k * 300 + n];
      acc0 += ab[0][k] * w;
      acc1 += ab[1][k] * w;
    }
    float c = beta1 * ws[WS_COLSUM + n] + ws[WS_CVEC + n];
    float v0 = a1 * acc0 + c, v1 = a1 * acc1 + c;
    ws[WS_Y1 + b0 * 300 + n] = v0 > 0.f ? v0 : 0.f;
    ws[WS_Y1 + (b0 + 1) * 300 + n] = v1 > 0.f ? v1 : 0.f;
  }
}

// ---------------- k6a: bn2 channel-0 partial stats ----------------
__global__ void k6a(float* __restrict__ ws) {
  int tid = threadIdx.x, bid = blockIdx.x;
  float s = 0.f, ss = 0.f;
  for (int i = bid * 256 + tid; i < BB * 300; i += 64 * 256) {
    float v = ws[WS_Y1 + i];
    s += v; ss += v * v;
  }
  for (int o = 32; o; o >>= 1) { s += __shfl_xor(s, o); ss += __shfl_xor(ss, o); }
  __shared__ float sh[2][4];
  int wave = tid >> 6, lane = tid & 63;
  if (!lane) { sh[0][wave] = s; sh[1][wave] = ss; }
  __syncthreads();
  if (!tid) {
    float S = 0.f, SS2 = 0.f;
    for (int w = 0; w < 4; ++w) { S += sh[0][w]; SS2 += sh[1][w]; }
    ws[WS_PART2 + bid * 2] = S;
    ws[WS_PART2 + bid * 2 + 1] = SS2;
  }
}

// ---------------- k7: bn2 finalize + consts (inline) + out ----------------
__global__ void k7(const float* __restrict__ g2, const float* __restrict__ b2,
                   float* __restrict__ out, const float* __restrict__ ws) {
  __shared__ float Gs[2400];
  __shared__ float sh[4];   // a2, b2s, c0, c1
  int tid = threadIdx.x;    // 64
  for (int i = tid; i < 2400; i += 64) Gs[i] = ws[WS_G + i];
  {
    float s = ws[WS_PART2 + tid * 2], ss = ws[WS_PART2 + tid * 2 + 1];
    for (int o = 32; o; o >>= 1) { s += __shfl_xor(s, o); ss += __shfl_xor(ss, o); }
    if (!tid) {
      float n = (float)(BB * 300);
      float mean = s / n, var = ss / n - mean * mean;
      float a = (1.f / sqrtf(var + 1e-5f)) * g2[0];
      sh[0] = a; sh[1] = b2[0] - a * mean;
    }
  }
  __syncthreads();
  if (tid < 2) {
    int c = tid;
    float sg1 = 0.f, sg2 = 0.f, sg3 = 0.f;
    for (int k = 0; k < 300; ++k) sg1 += Gs[k * 2 + c];
    for (int k = 300; k < 900; ++k) sg2 += Gs[k * 2 + c];
    for (int j = 0; j < 300; ++j) sg3 += ws[WS_CLS + j] * Gs[(900 + j) * 2 + c];
    sh[2 + c] = ws[WS_CST0 + c] + sg3 + sh[1] * sg1 + ws[WS_STATS + 1] * sg2;
  }
  __syncthreads();
  int b = blockIdx.x * 64 + tid;
  float a1 = ws[WS_STATS + 0], a2 = sh[0];
  float c0 = sh[2], c1 = sh[3];
  const float* y1 = ws + WS_Y1 + b * 300;
  const float* ms = ws + WS_MSA + b * 600;
  float o0 = 0.f, o1 = 0.f;
  for (int k = 0; k < 300; ++k) { float v = y1[k]; o0 += v * Gs[k * 2]; o1 += v * Gs[k * 2 + 1]; }
  float p0 = 0.f, p1 = 0.f;
  for (int j = 0; j < 600; ++j) { float v = ms[j]; p0 += v * Gs[(300 + j) * 2]; p1 += v * Gs[(300 + j) * 2 + 1]; }
  out[b * 2] = a2 * o0 + a1 * p0 + c0;
  out[b * 2 + 1] = a2 * o1 + a1 * p1 + c1;
}

extern "C" void kernel_launch(void* const* d_in, const int* in_sizes, int n_in,
                              void* d_out, int out_size, void* d_ws, size_t ws_size,
                              hipStream_t stream) {
  const float* x    = (const float*)d_in[0];
  const float* Wp   = (const float*)d_in[1];
  const float* bp   = (const float*)d_in[2];
  const float* pos  = (const float*)d_in[3];
  const float* cle  = (const float*)d_in[4];
  const float* Wq   = (const float*)d_in[5];
  const float* Wk   = (const float*)d_in[6];
  const float* Wv   = (const float*)d_in[7];
  const float* bn1g = (const float*)d_in[8];
  const float* bn1b = (const float*)d_in[9];
  const float* Wp1  = (const float*)d_in[10];
  const float* bp1  = (const float*)d_in[11];
  const float* bn2g = (const float*)d_in[12];
  const float* bn2b = (const float*)d_in[13];
  const float* f1W  = (const float*)d_in[14];
  const float* f1b  = (const float*)d_in[15];
  const float* f2W  = (const float*)d_in[16];
  const float* f2b  = (const float*)d_in[17];
  float* ws = (float*)d_ws;
  float* out = (float*)d_out;

  hipLaunchKernelGGL(kC1, dim3(29), dim3(256), 0, stream, pos, cle, Wq, Wp1, f1W, f2W, f1b, f2b, ws);
  hipLaunchKernelGGL(kC2, dim3(150), dim3(256), 0, stream, Wk, ws);
  hipLaunchKernelGGL(kC3, dim3(52), dim3(256), 0, stream, pos, bp1, ws);
  hipLaunchKernelGGL(kA, dim3(512), dim3(512), 0, stream, x, Wp, bp, pos, Wv, ws);
  hipLaunchKernelGGL(k4a, dim3(64), dim3(256), 0, stream, ws);
  hipLaunchKernelGGL(k5, dim3(256), dim3(256), 0, stream, Wp1, bn1g, bn1b, ws);
  hipLaunchKernelGGL(k6a, dim3(64), dim3(256), 0, stream, ws);
  hipLaunchKernelGGL(k7, dim3(8), dim3(64), 0, stream, bn2g, bn2b, out, ws);
}

// Round 10
// 119.548 us; speedup vs baseline: 2.1710x; 1.4433x over previous
//
#include <hip/hip_runtime.h>
#include <hip/hip_fp16.h>
#include <math.h>

#define BB 512
#define SS 100
#define DE 150
#define DM 300   // 2*D_E (also == D_IN)
#define LL 101
#define NH 2

typedef _Float16 f16x8 __attribute__((ext_vector_type(8)));
typedef float f32x4 __attribute__((ext_vector_type(4)));

// ---- ws layout (float offsets) ----
#define WS_CLS    0        // [300]
#define WS_QK     320      // [2][300]
#define WS_S0     960      // [2]
#define WS_CPOS   964      // [100][2]
#define WS_CVEC   1200     // [300]
#define WS_COLSUM 1536     // [300]
#define WS_CST0   1856     // [2]
#define WS_STATS  1860     // [0]=a1 [1]=beta1
#define WS_G      2176     // [1200][2]
#define WS_Q0     4608     // [2][300]
#define WS_P3     5248     // [15][2][300]
#define WS_PART1  14336    // [512][2]
#define WS_PART2  15360    // [256][2]
#define WS_MSA    16384                     // [512][600]
#define WS_Y1     (WS_MSA + 512*600)        // [512][300]  ends 477184
#define WS_WPF    477184   // fp16 [40][160][8] = 102,400 B (25,600 f32 slots)

// ---------------- kC1: q0 | Wp1 partials | cls | G=fc1@fc2 | Wpf ----------------
__global__ void kC1(const float* __restrict__ pos, const float* __restrict__ cle,
                    const float* __restrict__ Wq, const float* __restrict__ Wp1,
                    const float* __restrict__ Wp,
                    const float* __restrict__ f1W, const float* __restrict__ f2W,
                    const float* __restrict__ f1b, const float* __restrict__ f2b,
                    float* __restrict__ ws) {
  __shared__ float cls[DM];
  int b = blockIdx.x, tid = threadIdx.x;
  if (b < 18) {
    for (int i = tid; i < DM; i += 256) cls[i] = (i < DE) ? cle[i] : pos[i - DE];
    __syncthreads();
  }
  if (b < 3) {
    int idx = b * 256 + tid;
    if (idx < NH * DM) {
      int h = idx / DM, e = idx % DM;
      const float* w = Wq + h * DM * DM + e;
      float acc = 0.f;
      for (int d = 0; d < DM; ++d) acc += cls[d] * w[d * DM];
      ws[WS_Q0 + idx] = acc;
    }
  } else if (b < 18) {
    int kb = b - 3;
    for (int n = tid; n < DM; n += 256) {
      float cs = 0.f, cv = 0.f;
      for (int k = kb * 60; k < kb * 60 + 60; ++k) {
        float w = Wp1[k * 300 + n];
        if (k < 600) cs += w; else cv += cls[k - 600] * w;
      }
      ws[WS_P3 + kb * 600 + n] = cs;
      ws[WS_P3 + kb * 600 + 300 + n] = cv;
    }
  } else if (b == 18) {
    for (int i = tid; i < DM; i += 256)
      ws[WS_CLS + i] = (i < DE) ? cle[i] : pos[i - DE];
  } else if (b < 29) {
    int t = (b - 19) * 256 + tid;
    if (t < 2400) {
      int k = t >> 1, c = t & 1;
      const float* r = f1W + k * 512;
      float acc = 0.f;
      for (int m = 0; m < 512; ++m) acc += r[m] * f2W[m * 2 + c];
      ws[WS_G + t] = acc;
    } else if (t < 2402) {
      int c = t - 2400;
      float acc = f2b[c];
      for (int m = 0; m < 512; ++m) acc += f1b[m] * f2W[m * 2 + c];
      ws[WS_CST0 + c] = acc;
    }
  } else {
    // Wpf: fragment-ordered fp16 Wp. idx=(kq,n), Wpf[kq][n][j]=Wp[kq*8+j][n]
    int idx = (b - 29) * 256 + tid;       // < 6400
    int kq = idx / 160, n = idx % 160;
    f16x8 pk;
#pragma unroll
    for (int j = 0; j < 8; ++j) {
      int k = kq * 8 + j;
      float v = (k < DM && n < DE) ? Wp[k * DE + n] : 0.f;
      pk[j] = (_Float16)v;
    }
    *(f16x8*)((char*)ws + (size_t)WS_WPF * 4 + (size_t)idx * 16) = pk;
  }
}

// ---------------- kC2: qk[h][d] = Wk[h][d][:] . q0[h][:] (wave per output) ----------------
__global__ void kC2(const float* __restrict__ Wk, float* __restrict__ ws) {
  __shared__ float q0s[NH * DM];
  int tid = threadIdx.x;
  for (int i = tid; i < NH * DM; i += 256) q0s[i] = ws[WS_Q0 + i];
  __syncthreads();
  int wave = tid >> 6, lane = tid & 63;
  int idx = blockIdx.x * 4 + wave;            // < 600
  int h = idx / DM, d = idx % DM;
  const float* w = Wk + h * DM * DM + d * DM;
  const float* q = q0s + h * DM;
  float acc = 0.f;
  for (int e = lane; e < DM; e += 64) acc += w[e] * q[e];
  for (int o = 32; o; o >>= 1) acc += __shfl_xor(acc, o);
  if (!lane) ws[WS_QK + idx] = acc;
}

// ---------------- kC3: cpos | s0 | combine(colsum,cvec) ----------------
__global__ void kC3(const float* __restrict__ pos, const float* __restrict__ bp1,
                    float* __restrict__ ws) {
  int b = blockIdx.x, tid = threadIdx.x;
  int wave = tid >> 6, lane = tid & 63;
  if (b < 50) {
    int idx = b * 4 + wave;                   // < 200, = tt*2+h
    int tt = idx >> 1, h = idx & 1;
    const float* pr = pos + (tt + 1) * DE;
    const float* qk = ws + WS_QK + h * DM + DE;
    float acc = 0.f;
    for (int j = lane; j < DE; j += 64) acc += pr[j] * qk[j];
    for (int o = 32; o; o >>= 1) acc += __shfl_xor(acc, o);
    if (!lane) ws[WS_CPOS + idx] = acc;
  } else if (b == 50) {
    if (wave < NH) {
      float acc = 0.f;
      for (int d = lane; d < DM; d += 64) acc += ws[WS_CLS + d] * ws[WS_QK + wave * DM + d];
      for (int o = 32; o; o >>= 1) acc += __shfl_xor(acc, o);
      if (!lane) ws[WS_S0 + wave] = acc;
    }
  } else {
    for (int n = tid; n < DM; n += 256) {
      float cs = 0.f, cv = bp1[n];
      for (int p = 0; p < 15; ++p) {
        cs += ws[WS_P3 + p * 600 + n];
        cv += ws[WS_P3 + p * 600 + 300 + n];
      }
      ws[WS_COLSUM + n] = cs;
      ws[WS_CVEC + n] = cv;
    }
  }
}

// ---------------- kA: MFMA h-GEMM (dbuf LDS) -> scores -> softmax -> zbar -> msa + bn1 partial ----
// 512 threads = 8 waves (2M x 4N). Wp staged via linear 16B copies from precomputed Wpf;
// x staged float2->fp16. LDS union: GEMM dbuf (36,480B) aliases hb (written after loop).
// smem map: [0,10240) wpt0 | [10240,18240) xs0 | [18240,28480) wpt1 | [28480,36480) xs1
//           post-GEMM: [0,30400) hb | [36480,41600) aux | [41600,44000) zb
__launch_bounds__(512, 4)
__global__ void kA(const float* __restrict__ x, const float* __restrict__ bp,
                   const float* __restrict__ pos, const float* __restrict__ Wv,
                   float* __restrict__ ws) {
  __shared__ __align__(16) char smem[44000];
  __half (*hb)[DE + 2] = (__half(*)[DE + 2])smem;
  _Float16* wpt0 = (_Float16*)(smem);
  _Float16* xs0  = (_Float16*)(smem + 10240);
  _Float16* wpt1 = (_Float16*)(smem + 18240);
  _Float16* xs1  = (_Float16*)(smem + 28480);
  float* aux = (float*)(smem + 36480);
  float* zb  = (float*)(smem + 41600);

  int b = blockIdx.x, tid = threadIdx.x;
  int w = tid >> 6, lane = tid & 63;
  int l16 = lane & 15, lg = lane >> 4;
  int wm = w >> 2, wn = w & 3;
  int nnt = (wn < 3) ? 3 : 1;
  int nt0 = (wn < 3) ? wn * 3 : 9;

  const float* xb = x + b * (SS * DM);
  const char* wpf = (const char*)ws + (size_t)WS_WPF * 4;
  int rowl[4];
#pragma unroll
  for (int mt = 0; mt < 4; ++mt) {
    int r = wm * 64 + mt * 16 + l16;
    rowl[mt] = (r < SS) ? r : (SS - 1);
  }

  f32x4 acc[4][3];
#pragma unroll
  for (int mt = 0; mt < 4; ++mt)
#pragma unroll
    for (int nti = 0; nti < 3; ++nti) acc[mt][nti] = (f32x4){0.f, 0.f, 0.f, 0.f};

  float xr[4][2];
  float4 wa, wb2;

#define XLOAD(S)                                                               \
  { int kc_ = (S) * 32;                                                        \
    _Pragma("unroll")                                                          \
    for (int i_ = 0; i_ < 4; ++i_) {                                           \
      int t_ = tid + 512 * i_;                                                 \
      if (t_ < 1600) {                                                         \
        int r_ = t_ >> 4, c_ = t_ & 15, k_ = kc_ + 2 * c_;                     \
        if (k_ + 1 < DM) {                                                     \
          float2 v_ = *(const float2*)(xb + r_ * DM + k_);                     \
          xr[i_][0] = v_.x; xr[i_][1] = v_.y;                                  \
        } else {                                                               \
          xr[i_][0] = (k_ < DM) ? xb[r_ * DM + k_] : 0.f;                      \
          xr[i_][1] = 0.f;                                                     \
        } } } }

#define XWRITE(XP)                                                             \
  { _Pragma("unroll")                                                          \
    for (int i_ = 0; i_ < 4; ++i_) {                                           \
      int t_ = tid + 512 * i_;                                                 \
      if (t_ < 1600) {                                                         \
        int r_ = t_ >> 4, c_ = t_ & 15;                                        \
        *(__half2*)((char*)(XP) + r_ * 80 + c_ * 4) =                          \
            __floats2half2_rn(xr[i_][0], xr[i_][1]);                           \
      } } }

#define WLOAD(S)                                                               \
  { const char* s_ = wpf + (size_t)(S) * 10240;                                \
    wa = *(const float4*)(s_ + tid * 16);                                      \
    if (tid < 128) wb2 = *(const float4*)(s_ + (tid + 512) * 16); }

#define WWRITE(WP)                                                             \
  { *(float4*)((char*)(WP) + tid * 16) = wa;                                   \
    if (tid < 128) *(float4*)((char*)(WP) + (tid + 512) * 16) = wb2; }

  // prologue
  XLOAD(0); WLOAD(0);
  XWRITE(xs0); WWRITE(wpt0);
  __syncthreads();

  for (int s = 0; s < 10; ++s) {
    _Float16* wc = (s & 1) ? wpt1 : wpt0;
    _Float16* xc = (s & 1) ? xs1 : xs0;
    _Float16* wnx = (s & 1) ? wpt0 : wpt1;
    _Float16* xnx = (s & 1) ? xs0 : xs1;
    if (s < 9) { WLOAD(s + 1); XLOAD(s + 1); }
    f16x8 Bf[3];
#pragma unroll
    for (int nti = 0; nti < 3; ++nti)
      if (nti < nnt)
        Bf[nti] = *(const f16x8*)(wc + ((lg * 160 + (nt0 + nti) * 16 + l16) * 8));
#pragma unroll
    for (int mt = 0; mt < 4; ++mt) {
      f16x8 Af = *(const f16x8*)(xc + rowl[mt] * 40 + lg * 8);
#pragma unroll
      for (int nti = 0; nti < 3; ++nti)
        if (nti < nnt)
          acc[mt][nti] = __builtin_amdgcn_mfma_f32_16x16x32_f16(Af, Bf[nti], acc[mt][nti], 0, 0, 0);
    }
    if (s < 9) { WWRITE(wnx); XWRITE(xnx); }
    __syncthreads();
  }

  // ---- write hb = relu(acc + bp) in fp16 (aliases dead GEMM buffers) ----
#pragma unroll
  for (int nti = 0; nti < 3; ++nti) {
    if (nti < nnt) {
      int col = (nt0 + nti) * 16 + l16;
      float bpv = (col < DE) ? bp[col] : 0.f;
#pragma unroll
      for (int mt = 0; mt < 4; ++mt) {
        int rbase = wm * 64 + mt * 16 + lg * 4;
        f32x4 v = acc[mt][nti];
#pragma unroll
        for (int reg = 0; reg < 4; ++reg) {
          int row = rbase + reg;
          if (row < SS && col < DE) {
            float hv = v[reg] + bpv;
            hb[row][col] = __float2half(hv > 0.f ? hv : 0.f);
          }
        }
      }
    }
  }
  // reload aux: qk first-halves + cls
  for (int i = tid; i < DM; i += 512) {
    aux[i] = ws[WS_QK + (i / DE) * DM + (i % DE)];
    aux[DM + i] = ws[WS_CLS + i];
  }
  __syncthreads();

  // ---- phase 2: scores (hb as half2) ----
  if (tid < NH * SS) {
    int hh = tid / SS, tt = tid % SS;
    const __half2* hr = (const __half2*)&hb[tt][0];
    const float* qr = &aux[hh * DE];
    float s = 0.f;
    for (int j2 = 0; j2 < DE / 2; ++j2) {
      float2 hv = __half22float2(hr[j2]);
      float2 qv = *(const float2*)&qr[2 * j2];
      s += hv.x * qv.x + hv.y * qv.y;
    }
    aux[600 + hh * LL + tt + 1] = s + ws[WS_CPOS + tt * NH + hh];
  } else if (tid < NH * SS + NH) {
    int hh = tid - NH * SS;
    aux[600 + hh * LL] = ws[WS_S0 + hh];
  }
  __syncthreads();

  // ---- phase 3: softmax (one wave per head) ----
  if (w < NH) {
    float v0 = aux[600 + w * LL + lane];
    float v1 = (lane + 64 < LL) ? aux[600 + w * LL + lane + 64] : -1e30f;
    float m = fmaxf(v0, v1);
    for (int o = 32; o; o >>= 1) m = fmaxf(m, __shfl_xor(m, o));
    float e0 = expf(v0 - m);
    float e1 = (lane + 64 < LL) ? expf(v1 - m) : 0.f;
    float s = e0 + e1;
    for (int o = 32; o; o >>= 1) s += __shfl_xor(s, o);
    float inv = 1.f / s;
    aux[802 + w * LL + lane] = e0 * inv;
    if (lane + 64 < LL) aux[802 + w * LL + lane + 64] = e1 * inv;
  }
  __syncthreads();

  // ---- phase 4: zbar ----
  for (int o = tid; o < NH * DM; o += 512) {
    int hh = o / DM, d = o % DM;
    const float* p = &aux[802 + hh * LL];
    float acc2 = p[0] * aux[DM + d];
    if (d < DE) {
      for (int t = 1; t <= SS; ++t) acc2 += p[t] * __half2float(hb[t - 1][d]);
    } else {
      int dd = d - DE;
      for (int t = 1; t <= SS; ++t) acc2 += p[t] * pos[t * DE + dd];
    }
    zb[o] = acc2;
  }
  __syncthreads();

  // ---- phase 5: msa[b] = zb @ Wv + bn1 per-block partial (Σ, Σ²) ----
  float s_ = 0.f, ss_ = 0.f;
  for (int e = tid; e < NH * DM; e += 512) {
    int hh = e / DM, ee = e % DM;
    const float* wv = Wv + hh * DM * DM + ee;
    const float* z = zb + hh * DM;
    float t0 = 0.f, t1 = 0.f;
    for (int d = 0; d < DM; d += 2) {
      t0 += z[d] * wv[d * DM];
      t1 += z[d + 1] * wv[(d + 1) * DM];
    }
    float val = t0 + t1;
    ws[WS_MSA + b * 600 + e] = val;
    s_ += val; ss_ += val * val;
  }
  for (int o = 32; o; o >>= 1) { s_ += __shfl_xor(s_, o); ss_ += __shfl_xor(ss_, o); }
  if (!lane) { aux[1100 + w] = s_; aux[1108 + w] = ss_; }
  __syncthreads();
  if (!tid) {
    float S = 0.f, SS2 = 0.f;
    for (int i = 0; i < 8; ++i) { S += aux[1100 + i]; SS2 += aux[1108 + i]; }
    ws[WS_PART1 + b * 2] = S;
    ws[WS_PART1 + b * 2 + 1] = SS2;
  }
}

// ---------------- k5: bn1 finalize + y1 (split-K x2) + bn2 per-block partial ----------------
__launch_bounds__(512)
__global__ void k5(const float* __restrict__ Wp1, const float* __restrict__ g1,
                   const float* __restrict__ b1, float* __restrict__ ws) {
  __shared__ float ab[2][600];
  __shared__ float part[2][2][300];
  __shared__ float sh[2][8];
  __shared__ float s_a1, s_b1;
  int b0 = blockIdx.x * 2, tid = threadIdx.x;
  int wv = tid >> 6, ln = tid & 63;
  for (int i = tid; i < 1200; i += 512) ab[i / 600][i % 600] = ws[WS_MSA + b0 * 600 + i];
  {
    float s = ws[WS_PART1 + tid * 2], ss = ws[WS_PART1 + tid * 2 + 1];
    for (int o = 32; o; o >>= 1) { s += __shfl_xor(s, o); ss += __shfl_xor(ss, o); }
    if (!ln) { sh[0][wv] = s; sh[1][wv] = ss; }
  }
  __syncthreads();
  if (!tid) {
    float S = 0.f, SS2 = 0.f;
    for (int i = 0; i < 8; ++i) { S += sh[0][i]; SS2 += sh[1][i]; }
    float n = (float)(BB * 600);
    float mean = S / n, var = SS2 / n - mean * mean;
    float a = (1.f / sqrtf(var + 1e-5f)) * g1[0];
    s_a1 = a; s_b1 = b1[0] - a * mean;
    if (blockIdx.x == 0) { ws[WS_STATS + 0] = a; ws[WS_STATS + 1] = s_b1; }
  }
  __syncthreads();
  int g = tid >> 8, t = tid & 255;
  int kbeg = g * 300, kend = kbeg + 300;
  for (int n = t; n < 300; n += 256) {
    float a0 = 0.f, a1v = 0.f;
    for (int k = kbeg; k < kend; ++k) {
      float wq = Wp1[k * 300 + n];
      a0 += ab[0][k] * wq;
      a1v += ab[1][k] * wq;
    }
    part[g][0][n] = a0;
    part[g][1][n] = a1v;
  }
  __syncthreads();
  float a1 = s_a1, beta1 = s_b1;
  float s2 = 0.f, ss2 = 0.f;
  for (int n = tid; n < 300; n += 512) {
    float c = beta1 * ws[WS_COLSUM + n] + ws[WS_CVEC + n];
    float v0 = a1 * (part[0][0][n] + part[1][0][n]) + c;
    float v1 = a1 * (part[0][1][n] + part[1][1][n]) + c;
    v0 = v0 > 0.f ? v0 : 0.f;
    v1 = v1 > 0.f ? v1 : 0.f;
    ws[WS_Y1 + b0 * 300 + n] = v0;
    ws[WS_Y1 + (b0 + 1) * 300 + n] = v1;
    s2 += v0 + v1; ss2 += v0 * v0 + v1 * v1;
  }
  for (int o = 32; o; o >>= 1) { s2 += __shfl_xor(s2, o); ss2 += __shfl_xor(ss2, o); }
  if (!ln) { sh[0][wv] = s2; sh[1][wv] = ss2; }
  __syncthreads();
  if (!tid) {
    float S = 0.f, SS2 = 0.f;
    for (int i = 0; i < 8; ++i) { S += sh[0][i]; SS2 += sh[1][i]; }
    ws[WS_PART2 + blockIdx.x * 2] = S;
    ws[WS_PART2 + blockIdx.x * 2 + 1] = SS2;
  }
}

// ---------------- k7: bn2 finalize + consts + out (wave per batch) ----------------
__launch_bounds__(256)
__global__ void k7(const float* __restrict__ g2, const float* __restrict__ b2,
                   float* __restrict__ out, const float* __restrict__ ws) {
  __shared__ float Gs[2400];
  __shared__ float sh[2][4];
  __shared__ float cc[4];   // a2, b2s, c0, c1
  int tid = threadIdx.x, wv = tid >> 6, ln = tid & 63;
  for (int i = tid; i < 2400; i += 256) Gs[i] = ws[WS_G + i];
  {
    float s = ws[WS_PART2 + tid * 2], ss = ws[WS_PART2 + tid * 2 + 1];
    for (int o = 32; o; o >>= 1) { s += __shfl_xor(s, o); ss += __shfl_xor(ss, o); }
    if (!ln) { sh[0][wv] = s; sh[1][wv] = ss; }
  }
  __syncthreads();
  if (!tid) {
    float S = 0.f, SS2 = 0.f;
    for (int i = 0; i < 4; ++i) { S += sh[0][i]; SS2 += sh[1][i]; }
    float n = (float)(BB * 300);
    float mean = S / n, var = SS2 / n - mean * mean;
    float a = (1.f / sqrtf(var + 1e-5f)) * g2[0];
    cc[0] = a; cc[1] = b2[0] - a * mean;
  }
  __syncthreads();
  if (tid < 2) {
    int c = tid;
    float sg1 = 0.f, sg2 = 0.f, sg3 = 0.f;
    for (int k = 0; k < 300; ++k) sg1 += Gs[k * 2 + c];
    for (int k = 300; k < 900; ++k) sg2 += Gs[k * 2 + c];
    for (int j = 0; j < 300; ++j) sg3 += ws[WS_CLS + j] * Gs[(900 + j) * 2 + c];
    cc[2 + c] = ws[WS_CST0 + c] + sg3 + cc[1] * sg1 + ws[WS_STATS + 1] * sg2;
  }
  __syncthreads();
  int b = blockIdx.x * 4 + wv;
  float a1 = ws[WS_STATS + 0], a2 = cc[0];
  const float* y1 = ws + WS_Y1 + b * 300;
  const float* ms = ws + WS_MSA + b * 600;
  float o0 = 0.f, o1 = 0.f, p0 = 0.f, p1 = 0.f;
  for (int k = ln; k < 300; k += 64) { float v = y1[k]; o0 += v * Gs[k * 2]; o1 += v * Gs[k * 2 + 1]; }
  for (int j = ln; j < 600; j += 64) { float v = ms[j]; p0 += v * Gs[(300 + j) * 2]; p1 += v * Gs[(300 + j) * 2 + 1]; }
  for (int o = 32; o; o >>= 1) {
    o0 += __shfl_xor(o0, o); o1 += __shfl_xor(o1, o);
    p0 += __shfl_xor(p0, o); p1 += __shfl_xor(p1, o);
  }
  if (!ln) {
    out[b * 2] = a2 * o0 + a1 * p0 + cc[2];
    out[b * 2 + 1] = a2 * o1 + a1 * p1 + cc[3];
  }
}

extern "C" void kernel_launch(void* const* d_in, const int* in_sizes, int n_in,
                              void* d_out, int out_size, void* d_ws, size_t ws_size,
                              hipStream_t stream) {
  const float* x    = (const float*)d_in[0];
  const float* Wp   = (const float*)d_in[1];
  const float* bp   = (const float*)d_in[2];
  const float* pos  = (const float*)d_in[3];
  const float* cle  = (const float*)d_in[4];
  const float* Wq   = (const float*)d_in[5];
  const float* Wk   = (const float*)d_in[6];
  const float* Wv   = (const float*)d_in[7];
  const float* bn1g = (const float*)d_in[8];
  const float* bn1b = (const float*)d_in[9];
  const float* Wp1  = (const float*)d_in[10];
  const float* bp1  = (const float*)d_in[11];
  const float* bn2g = (const float*)d_in[12];
  const float* bn2b = (const float*)d_in[13];
  const float* f1W  = (const float*)d_in[14];
  const float* f1b  = (const float*)d_in[15];
  const float* f2W  = (const float*)d_in[16];
  const float* f2b  = (const float*)d_in[17];
  float* ws = (float*)d_ws;
  float* out = (float*)d_out;

  hipLaunchKernelGGL(kC1, dim3(54), dim3(256), 0, stream, pos, cle, Wq, Wp1, Wp, f1W, f2W, f1b, f2b, ws);
  hipLaunchKernelGGL(kC2, dim3(150), dim3(256), 0, stream, Wk, ws);
  hipLaunchKernelGGL(kC3, dim3(52), dim3(256), 0, stream, pos, bp1, ws);
  hipLaunchKernelGGL(kA, dim3(512), dim3(512), 0, stream, x, bp, pos, Wv, ws);
  hipLaunchKernelGGL(k5, dim3(256), dim3(512), 0, stream, Wp1, bn1g, bn1b, ws);
  hipLaunchKernelGGL(k7, dim3(128), dim3(256), 0, stream, bn2g, bn2b, out, ws);
}

// Round 11
// 117.309 us; speedup vs baseline: 2.2124x; 1.0191x over previous
//
#include <hip/hip_runtime.h>
#include <hip/hip_fp16.h>
#include <math.h>

#define BB 512
#define SS 100
#define DE 150
#define DM 300   // 2*D_E (also == D_IN)
#define LL 101
#define NH 2

typedef _Float16 f16x8 __attribute__((ext_vector_type(8)));
typedef float f32x4 __attribute__((ext_vector_type(4)));

// ---- ws layout (float offsets) ----
#define WS_CLS    0        // [300]
#define WS_QK     320      // [2][300]
#define WS_S0     960      // [2]
#define WS_CPOS   964      // [100][2]
#define WS_CVEC   1200     // [300]
#define WS_COLSUM 1536     // [300]
#define WS_CST0   1856     // [2]
#define WS_STATS  1860     // [0]=a1 [1]=beta1
#define WS_G      2176     // [1200][2]
#define WS_Q0     4608     // [2][300]
#define WS_P3     5248     // [15][2][300]
#define WS_PART1  14336    // [16][2]   (kV blocks)
#define WS_PART2  15360    // [256][2]
#define WS_MSA    16384                     // [512][600]
#define WS_Y1     (WS_MSA + 512*600)        // [512][300]  ends 477184
#define WS_WPF    477184   // fp16 [40][160][8] = 102,400 B (25,600 f32)
#define WS_WVF    502784   // fp16 [2][40][320][8] = 409,600 B (102,400 f32)
#define WS_ZB16   605184   // fp16 [2][512][320] = 655,360 B (163,840 f32)

// ---------------- kC1: q0 | Wp1 partials | cls | G | Wpf | Wvf ----------------
__global__ void kC1(const float* __restrict__ pos, const float* __restrict__ cle,
                    const float* __restrict__ Wq, const float* __restrict__ Wp1,
                    const float* __restrict__ Wp, const float* __restrict__ Wv,
                    const float* __restrict__ f1W, const float* __restrict__ f2W,
                    const float* __restrict__ f1b, const float* __restrict__ f2b,
                    float* __restrict__ ws) {
  __shared__ float cls[DM];
  int b = blockIdx.x, tid = threadIdx.x;
  if (b < 18) {
    for (int i = tid; i < DM; i += 256) cls[i] = (i < DE) ? cle[i] : pos[i - DE];
    __syncthreads();
  }
  if (b < 3) {
    int idx = b * 256 + tid;
    if (idx < NH * DM) {
      int h = idx / DM, e = idx % DM;
      const float* w = Wq + h * DM * DM + e;
      float acc = 0.f;
      for (int d = 0; d < DM; ++d) acc += cls[d] * w[d * DM];
      ws[WS_Q0 + idx] = acc;
    }
  } else if (b < 18) {
    int kb = b - 3;
    for (int n = tid; n < DM; n += 256) {
      float cs = 0.f, cv = 0.f;
      for (int k = kb * 60; k < kb * 60 + 60; ++k) {
        float w = Wp1[k * 300 + n];
        if (k < 600) cs += w; else cv += cls[k - 600] * w;
      }
      ws[WS_P3 + kb * 600 + n] = cs;
      ws[WS_P3 + kb * 600 + 300 + n] = cv;
    }
  } else if (b == 18) {
    for (int i = tid; i < DM; i += 256)
      ws[WS_CLS + i] = (i < DE) ? cle[i] : pos[i - DE];
  } else if (b < 29) {
    int t = (b - 19) * 256 + tid;
    if (t < 2400) {
      int k = t >> 1, c = t & 1;
      const float* r = f1W + k * 512;
      float acc = 0.f;
      for (int m = 0; m < 512; ++m) acc += r[m] * f2W[m * 2 + c];
      ws[WS_G + t] = acc;
    } else if (t < 2402) {
      int c = t - 2400;
      float acc = f2b[c];
      for (int m = 0; m < 512; ++m) acc += f1b[m] * f2W[m * 2 + c];
      ws[WS_CST0 + c] = acc;
    }
  } else if (b < 54) {
    // Wpf: fragment-ordered fp16 Wp. Wpf[kq][n][j] = Wp[kq*8+j][n]
    int idx = (b - 29) * 256 + tid;       // < 6400
    int kq = idx / 160, n = idx % 160;
    f16x8 pk;
#pragma unroll
    for (int j = 0; j < 8; ++j) {
      int k = kq * 8 + j;
      float v = (k < DM && n < DE) ? Wp[k * DE + n] : 0.f;
      pk[j] = (_Float16)v;
    }
    *(f16x8*)((char*)ws + (size_t)WS_WPF * 4 + (size_t)idx * 16) = pk;
  } else {
    // Wvf: fragment-ordered fp16 Wv. Wvf[h][kq][n][j] = Wv[h][kq*8+j][n], pad K->320, N->320
    int idx = (b - 54) * 256 + tid;       // < 25600
    int h = idx / 12800, rem = idx % 12800;
    int kq = rem / 320, n = rem % 320;
    f16x8 pk;
#pragma unroll
    for (int j = 0; j < 8; ++j) {
      int k = kq * 8 + j;
      float v = (k < DM && n < DM) ? Wv[h * DM * DM + k * DM + n] : 0.f;
      pk[j] = (_Float16)v;
    }
    *(f16x8*)((char*)ws + (size_t)WS_WVF * 4 + (size_t)idx * 16) = pk;
  }
}

// ---------------- kC2: qk[h][d] = Wk[h][d][:] . q0[h][:] (wave per output) ----------------
__global__ void kC2(const float* __restrict__ Wk, float* __restrict__ ws) {
  __shared__ float q0s[NH * DM];
  int tid = threadIdx.x;
  for (int i = tid; i < NH * DM; i += 256) q0s[i] = ws[WS_Q0 + i];
  __syncthreads();
  int wave = tid >> 6, lane = tid & 63;
  int idx = blockIdx.x * 4 + wave;            // < 600
  int h = idx / DM, d = idx % DM;
  const float* w = Wk + h * DM * DM + d * DM;
  const float* q = q0s + h * DM;
  float acc = 0.f;
  for (int e = lane; e < DM; e += 64) acc += w[e] * q[e];
  for (int o = 32; o; o >>= 1) acc += __shfl_xor(acc, o);
  if (!lane) ws[WS_QK + idx] = acc;
}

// ---------------- kC3: cpos | s0 | combine(colsum,cvec) ----------------
__global__ void kC3(const float* __restrict__ pos, const float* __restrict__ bp1,
                    float* __restrict__ ws) {
  int b = blockIdx.x, tid = threadIdx.x;
  int wave = tid >> 6, lane = tid & 63;
  if (b < 50) {
    int idx = b * 4 + wave;                   // < 200, = tt*2+h
    int tt = idx >> 1, h = idx & 1;
    const float* pr = pos + (tt + 1) * DE;
    const float* qk = ws + WS_QK + h * DM + DE;
    float acc = 0.f;
    for (int j = lane; j < DE; j += 64) acc += pr[j] * qk[j];
    for (int o = 32; o; o >>= 1) acc += __shfl_xor(acc, o);
    if (!lane) ws[WS_CPOS + idx] = acc;
  } else if (b == 50) {
    if (wave < NH) {
      float acc = 0.f;
      for (int d = lane; d < DM; d += 64) acc += ws[WS_CLS + d] * ws[WS_QK + wave * DM + d];
      for (int o = 32; o; o >>= 1) acc += __shfl_xor(acc, o);
      if (!lane) ws[WS_S0 + wave] = acc;
    }
  } else {
    for (int n = tid; n < DM; n += 256) {
      float cs = 0.f, cv = bp1[n];
      for (int p = 0; p < 15; ++p) {
        cs += ws[WS_P3 + p * 600 + n];
        cv += ws[WS_P3 + p * 600 + 300 + n];
      }
      ws[WS_COLSUM + n] = cs;
      ws[WS_CVEC + n] = cv;
    }
  }
}

// ---------------- kA: MFMA h-GEMM (dbuf LDS) -> scores -> softmax -> zbar16 (global) ----
// 512 threads = 8 waves (2M x 4N). LDS union: GEMM dbuf aliases hb.
// smem map: [0,10240) wpt0 | [10240,18240) xs0 | [18240,28480) wpt1 | [28480,36480) xs1
//           post-GEMM: [0,30400) hb | [36480,41600) aux
__launch_bounds__(512, 4)
__global__ void kA(const float* __restrict__ x, const float* __restrict__ bp,
                   const float* __restrict__ pos, float* __restrict__ ws) {
  __shared__ __align__(16) char smem[41600];
  __half (*hb)[DE + 2] = (__half(*)[DE + 2])smem;
  _Float16* wpt0 = (_Float16*)(smem);
  _Float16* xs0  = (_Float16*)(smem + 10240);
  _Float16* wpt1 = (_Float16*)(smem + 18240);
  _Float16* xs1  = (_Float16*)(smem + 28480);
  float* aux = (float*)(smem + 36480);

  int b = blockIdx.x, tid = threadIdx.x;
  int w = tid >> 6, lane = tid & 63;
  int l16 = lane & 15, lg = lane >> 4;
  int wm = w >> 2, wn = w & 3;
  int nnt = (wn < 3) ? 3 : 1;
  int nt0 = (wn < 3) ? wn * 3 : 9;

  const float* xb = x + b * (SS * DM);
  const char* wpf = (const char*)ws + (size_t)WS_WPF * 4;
  int rowl[4];
#pragma unroll
  for (int mt = 0; mt < 4; ++mt) {
    int r = wm * 64 + mt * 16 + l16;
    rowl[mt] = (r < SS) ? r : (SS - 1);
  }

  f32x4 acc[4][3];
#pragma unroll
  for (int mt = 0; mt < 4; ++mt)
#pragma unroll
    for (int nti = 0; nti < 3; ++nti) acc[mt][nti] = (f32x4){0.f, 0.f, 0.f, 0.f};

  float xr[4][2];
  float4 wa, wb2;

#define XLOAD(S)                                                               \
  { int kc_ = (S) * 32;                                                        \
    _Pragma("unroll")                                                          \
    for (int i_ = 0; i_ < 4; ++i_) {                                           \
      int t_ = tid + 512 * i_;                                                 \
      if (t_ < 1600) {                                                         \
        int r_ = t_ >> 4, c_ = t_ & 15, k_ = kc_ + 2 * c_;                     \
        if (k_ + 1 < DM) {                                                     \
          float2 v_ = *(const float2*)(xb + r_ * DM + k_);                     \
          xr[i_][0] = v_.x; xr[i_][1] = v_.y;                                  \
        } else {                                                               \
          xr[i_][0] = (k_ < DM) ? xb[r_ * DM + k_] : 0.f;                      \
          xr[i_][1] = 0.f;                                                     \
        } } } }

#define XWRITE(XP)                                                             \
  { _Pragma("unroll")                                                          \
    for (int i_ = 0; i_ < 4; ++i_) {                                           \
      int t_ = tid + 512 * i_;                                                 \
      if (t_ < 1600) {                                                         \
        int r_ = t_ >> 4, c_ = t_ & 15;                                        \
        *(__half2*)((char*)(XP) + r_ * 80 + c_ * 4) =                          \
            __floats2half2_rn(xr[i_][0], xr[i_][1]);                           \
      } } }

#define WLOAD(S)                                                               \
  { const char* s_ = wpf + (size_t)(S) * 10240;                                \
    wa = *(const float4*)(s_ + tid * 16);                                      \
    if (tid < 128) wb2 = *(const float4*)(s_ + (tid + 512) * 16); }

#define WWRITE(WP)                                                             \
  { *(float4*)((char*)(WP) + tid * 16) = wa;                                   \
    if (tid < 128) *(float4*)((char*)(WP) + (tid + 512) * 16) = wb2; }

  // prologue
  XLOAD(0); WLOAD(0);
  XWRITE(xs0); WWRITE(wpt0);
  __syncthreads();

  for (int s = 0; s < 10; ++s) {
    _Float16* wc = (s & 1) ? wpt1 : wpt0;
    _Float16* xc = (s & 1) ? xs1 : xs0;
    _Float16* wnx = (s & 1) ? wpt0 : wpt1;
    _Float16* xnx = (s & 1) ? xs0 : xs1;
    if (s < 9) { WLOAD(s + 1); XLOAD(s + 1); }
    f16x8 Bf[3];
#pragma unroll
    for (int nti = 0; nti < 3; ++nti)
      if (nti < nnt)
        Bf[nti] = *(const f16x8*)(wc + ((lg * 160 + (nt0 + nti) * 16 + l16) * 8));
#pragma unroll
    for (int mt = 0; mt < 4; ++mt) {
      f16x8 Af = *(const f16x8*)(xc + rowl[mt] * 40 + lg * 8);
#pragma unroll
      for (int nti = 0; nti < 3; ++nti)
        if (nti < nnt)
          acc[mt][nti] = __builtin_amdgcn_mfma_f32_16x16x32_f16(Af, Bf[nti], acc[mt][nti], 0, 0, 0);
    }
    if (s < 9) { WWRITE(wnx); XWRITE(xnx); }
    __syncthreads();
  }

  // ---- write hb = relu(acc + bp) in fp16 (aliases dead GEMM buffers) ----
#pragma unroll
  for (int nti = 0; nti < 3; ++nti) {
    if (nti < nnt) {
      int col = (nt0 + nti) * 16 + l16;
      float bpv = (col < DE) ? bp[col] : 0.f;
#pragma unroll
      for (int mt = 0; mt < 4; ++mt) {
        int rbase = wm * 64 + mt * 16 + lg * 4;
        f32x4 v = acc[mt][nti];
#pragma unroll
        for (int reg = 0; reg < 4; ++reg) {
          int row = rbase + reg;
          if (row < SS && col < DE) {
            float hv = v[reg] + bpv;
            hb[row][col] = __float2half(hv > 0.f ? hv : 0.f);
          }
        }
      }
    }
  }
  // reload aux: qk first-halves + cls
  for (int i = tid; i < DM; i += 512) {
    aux[i] = ws[WS_QK + (i / DE) * DM + (i % DE)];
    aux[DM + i] = ws[WS_CLS + i];
  }
  __syncthreads();

  // ---- phase 2: scores (hb as half2) ----
  if (tid < NH * SS) {
    int hh = tid / SS, tt = tid % SS;
    const __half2* hr = (const __half2*)&hb[tt][0];
    const float* qr = &aux[hh * DE];
    float s = 0.f;
    for (int j2 = 0; j2 < DE / 2; ++j2) {
      float2 hv = __half22float2(hr[j2]);
      float2 qv = *(const float2*)&qr[2 * j2];
      s += hv.x * qv.x + hv.y * qv.y;
    }
    aux[600 + hh * LL + tt + 1] = s + ws[WS_CPOS + tt * NH + hh];
  } else if (tid < NH * SS + NH) {
    int hh = tid - NH * SS;
    aux[600 + hh * LL] = ws[WS_S0 + hh];
  }
  __syncthreads();

  // ---- phase 3: softmax (one wave per head) ----
  if (w < NH) {
    float v0 = aux[600 + w * LL + lane];
    float v1 = (lane + 64 < LL) ? aux[600 + w * LL + lane + 64] : -1e30f;
    float m = fmaxf(v0, v1);
    for (int o = 32; o; o >>= 1) m = fmaxf(m, __shfl_xor(m, o));
    float e0 = expf(v0 - m);
    float e1 = (lane + 64 < LL) ? expf(v1 - m) : 0.f;
    float s = e0 + e1;
    for (int o = 32; o; o >>= 1) s += __shfl_xor(s, o);
    float inv = 1.f / s;
    aux[802 + w * LL + lane] = e0 * inv;
    if (lane + 64 < LL) aux[802 + w * LL + lane + 64] = e1 * inv;
  }
  __syncthreads();

  // ---- phase 4: zbar -> global fp16 [h][512][320] ----
  __half* zb16 = (__half*)((char*)ws + (size_t)WS_ZB16 * 4);
  for (int o = tid; o < NH * DM; o += 512) {
    int hh = o / DM, d = o % DM;
    const float* p = &aux[802 + hh * LL];
    float acc2 = p[0] * aux[DM + d];
    if (d < DE) {
      for (int t = 1; t <= SS; ++t) acc2 += p[t] * __half2float(hb[t - 1][d]);
    } else {
      int dd = d - DE;
      for (int t = 1; t <= SS; ++t) acc2 += p[t] * pos[t * DE + dd];
    }
    zb16[((size_t)hh * 512 + b) * 320 + d] = __float2half(acc2);
  }
  if (tid < 40) {
    int hh = tid / 20, dd = 300 + tid % 20;
    zb16[((size_t)hh * 512 + b) * 320 + dd] = __float2half(0.f);
  }
}

// ---------------- kV: msa = zbar16 @ Wvf (MFMA, no LDS staging) + bn1 partials ----------------
// grid 16 = mtile(4) x nb(2) x h(2); 512 threads = 8 waves (2M x 4N), tile 128M x 160N.
__launch_bounds__(512, 4)
__global__ void kV(float* __restrict__ ws) {
  __shared__ float shp[2][8];
  int blk = blockIdx.x;
  int mtile = blk >> 2, nb = (blk >> 1) & 1, h = blk & 1;
  int tid = threadIdx.x;
  int w = tid >> 6, lane = tid & 63;
  int l16 = lane & 15, lg = lane >> 4;
  int wm = w >> 2, wn = w & 3;
  int nnt = (wn < 3) ? 3 : 1;
  int nt0 = (wn < 3) ? wn * 3 : 9;
  int mbase = mtile * 128;

  const __half* zb16 = (const __half*)((const char*)ws + (size_t)WS_ZB16 * 4) + (size_t)h * 512 * 320;
  const __half* wvf  = (const __half*)((const char*)ws + (size_t)WS_WVF * 4) + (size_t)h * 40 * 320 * 8;

  int brow[4];
#pragma unroll
  for (int mt = 0; mt < 4; ++mt) brow[mt] = mbase + wm * 64 + mt * 16 + l16;

  f32x4 acc[4][3];
#pragma unroll
  for (int mt = 0; mt < 4; ++mt)
#pragma unroll
    for (int nti = 0; nti < 3; ++nti) acc[mt][nti] = (f32x4){0.f, 0.f, 0.f, 0.f};

  for (int s = 0; s < 10; ++s) {
    f16x8 Bf[3];
#pragma unroll
    for (int nti = 0; nti < 3; ++nti)
      if (nti < nnt) {
        int n = nb * 160 + (nt0 + nti) * 16 + l16;
        Bf[nti] = *(const f16x8*)&wvf[((size_t)(s * 4 + lg) * 320 + n) * 8];
      }
#pragma unroll
    for (int mt = 0; mt < 4; ++mt) {
      f16x8 Af = *(const f16x8*)&zb16[(size_t)brow[mt] * 320 + s * 32 + lg * 8];
#pragma unroll
      for (int nti = 0; nti < 3; ++nti)
        if (nti < nnt)
          acc[mt][nti] = __builtin_amdgcn_mfma_f32_16x16x32_f16(Af, Bf[nti], acc[mt][nti], 0, 0, 0);
    }
  }

  // epilogue: msa writes + bn1 partial (sum, sumsq) over this block's outputs
  float s_ = 0.f, ss_ = 0.f;
#pragma unroll
  for (int nti = 0; nti < 3; ++nti) {
    if (nti < nnt) {
      int col = nb * 160 + (nt0 + nti) * 16 + l16;
      if (col < DM) {
#pragma unroll
        for (int mt = 0; mt < 4; ++mt) {
          int rbase = mbase + wm * 64 + mt * 16 + lg * 4;
          f32x4 v = acc[mt][nti];
#pragma unroll
          for (int reg = 0; reg < 4; ++reg) {
            int row = rbase + reg;
            float val = v[reg];
            ws[WS_MSA + row * 600 + h * DM + col] = val;
            s_ += val; ss_ += val * val;
          }
        }
      }
    }
  }
  for (int o = 32; o; o >>= 1) { s_ += __shfl_xor(s_, o); ss_ += __shfl_xor(ss_, o); }
  if (!lane) { shp[0][w] = s_; shp[1][w] = ss_; }
  __syncthreads();
  if (!tid) {
    float S = 0.f, SS2 = 0.f;
    for (int i = 0; i < 8; ++i) { S += shp[0][i]; SS2 += shp[1][i]; }
    ws[WS_PART1 + blk * 2] = S;
    ws[WS_PART1 + blk * 2 + 1] = SS2;
  }
}

// ---------------- k5: bn1 finalize + y1 (split-K x2) + bn2 per-block partial ----------------
__launch_bounds__(512)
__global__ void k5(const float* __restrict__ Wp1, const float* __restrict__ g1,
                   const float* __restrict__ b1, float* __restrict__ ws) {
  __shared__ float ab[2][600];
  __shared__ float part[2][2][300];
  __shared__ float sh[2][8];
  __shared__ float s_a1, s_b1;
  int b0 = blockIdx.x * 2, tid = threadIdx.x;
  int wv = tid >> 6, ln = tid & 63;
  for (int i = tid; i < 1200; i += 512) ab[i / 600][i % 600] = ws[WS_MSA + b0 * 600 + i];
  {
    float s = 0.f, ss = 0.f;
    if (tid < 16) { s = ws[WS_PART1 + tid * 2]; ss = ws[WS_PART1 + tid * 2 + 1]; }
    for (int o = 32; o; o >>= 1) { s += __shfl_xor(s, o); ss += __shfl_xor(ss, o); }
    if (!ln) { sh[0][wv] = s; sh[1][wv] = ss; }
  }
  __syncthreads();
  if (!tid) {
    float S = 0.f, SS2 = 0.f;
    for (int i = 0; i < 8; ++i) { S += sh[0][i]; SS2 += sh[1][i]; }
    float n = (float)(BB * 600);
    float mean = S / n, var = SS2 / n - mean * mean;
    float a = (1.f / sqrtf(var + 1e-5f)) * g1[0];
    s_a1 = a; s_b1 = b1[0] - a * mean;
    if (blockIdx.x == 0) { ws[WS_STATS + 0] = a; ws[WS_STATS + 1] = s_b1; }
  }
  __syncthreads();
  int g = tid >> 8, t = tid & 255;
  int kbeg = g * 300, kend = kbeg + 300;
  for (int n = t; n < 300; n += 256) {
    float a0 = 0.f, a1v = 0.f;
    for (int k = kbeg; k < kend; ++k) {
      float wq = Wp1[k * 300 + n];
      a0 += ab[0][k] * wq;
      a1v += ab[1][k] * wq;
    }
    part[g][0][n] = a0;
    part[g][1][n] = a1v;
  }
  __syncthreads();
  float a1 = s_a1, beta1 = s_b1;
  float s2 = 0.f, ss2 = 0.f;
  for (int n = tid; n < 300; n += 512) {
    float c = beta1 * ws[WS_COLSUM + n] + ws[WS_CVEC + n];
    float v0 = a1 * (part[0][0][n] + part[1][0][n]) + c;
    float v1 = a1 * (part[0][1][n] + part[1][1][n]) + c;
    v0 = v0 > 0.f ? v0 : 0.f;
    v1 = v1 > 0.f ? v1 : 0.f;
    ws[WS_Y1 + b0 * 300 + n] = v0;
    ws[WS_Y1 + (b0 + 1) * 300 + n] = v1;
    s2 += v0 + v1; ss2 += v0 * v0 + v1 * v1;
  }
  for (int o = 32; o; o >>= 1) { s2 += __shfl_xor(s2, o); ss2 += __shfl_xor(ss2, o); }
  if (!ln) { sh[0][wv] = s2; sh[1][wv] = ss2; }
  __syncthreads();
  if (!tid) {
    float S = 0.f, SS2 = 0.f;
    for (int i = 0; i < 8; ++i) { S += sh[0][i]; SS2 += sh[1][i]; }
    ws[WS_PART2 + blockIdx.x * 2] = S;
    ws[WS_PART2 + blockIdx.x * 2 + 1] = SS2;
  }
}

// ---------------- k7: bn2 finalize + consts + out (wave per batch) ----------------
__launch_bounds__(256)
__global__ void k7(const float* __restrict__ g2, const float* __restrict__ b2,
                   float* __restrict__ out, const float* __restrict__ ws) {
  __shared__ float Gs[2400];
  __shared__ float sh[2][4];
  __shared__ float cc[4];   // a2, b2s, c0, c1
  int tid = threadIdx.x, wv = tid >> 6, ln = tid & 63;
  for (int i = tid; i < 2400; i += 256) Gs[i] = ws[WS_G + i];
  {
    float s = ws[WS_PART2 + tid * 2], ss = ws[WS_PART2 + tid * 2 + 1];
    for (int o = 32; o; o >>= 1) { s += __shfl_xor(s, o); ss += __shfl_xor(ss, o); }
    if (!ln) { sh[0][wv] = s; sh[1][wv] = ss; }
  }
  __syncthreads();
  if (!tid) {
    float S = 0.f, SS2 = 0.f;
    for (int i = 0; i < 4; ++i) { S += sh[0][i]; SS2 += sh[1][i]; }
    float n = (float)(BB * 300);
    float mean = S / n, var = SS2 / n - mean * mean;
    float a = (1.f / sqrtf(var + 1e-5f)) * g2[0];
    cc[0] = a; cc[1] = b2[0] - a * mean;
  }
  __syncthreads();
  if (tid < 2) {
    int c = tid;
    float sg1 = 0.f, sg2 = 0.f, sg3 = 0.f;
    for (int k = 0; k < 300; ++k) sg1 += Gs[k * 2 + c];
    for (int k = 300; k < 900; ++k) sg2 += Gs[k * 2 + c];
    for (int j = 0; j < 300; ++j) sg3 += ws[WS_CLS + j] * Gs[(900 + j) * 2 + c];
    cc[2 + c] = ws[WS_CST0 + c] + sg3 + cc[1] * sg1 + ws[WS_STATS + 1] * sg2;
  }
  __syncthreads();
  int b = blockIdx.x * 4 + wv;
  float a1 = ws[WS_STATS + 0], a2 = cc[0];
  const float* y1 = ws + WS_Y1 + b * 300;
  const float* ms = ws + WS_MSA + b * 600;
  float o0 = 0.f, o1 = 0.f, p0 = 0.f, p1 = 0.f;
  for (int k = ln; k < 300; k += 64) { float v = y1[k]; o0 += v * Gs[k * 2]; o1 += v * Gs[k * 2 + 1]; }
  for (int j = ln; j < 600; j += 64) { float v = ms[j]; p0 += v * Gs[(300 + j) * 2]; p1 += v * Gs[(300 + j) * 2 + 1]; }
  for (int o = 32; o; o >>= 1) {
    o0 += __shfl_xor(o0, o); o1 += __shfl_xor(o1, o);
    p0 += __shfl_xor(p0, o); p1 += __shfl_xor(p1, o);
  }
  if (!ln) {
    out[b * 2] = a2 * o0 + a1 * p0 + cc[2];
    out[b * 2 + 1] = a2 * o1 + a1 * p1 + cc[3];
  }
}

extern "C" void kernel_launch(void* const* d_in, const int* in_sizes, int n_in,
                              void* d_out, int out_size, void* d_ws, size_t ws_size,
                              hipStream_t stream) {
  const float* x    = (const float*)d_in[0];
  const float* Wp   = (const float*)d_in[1];
  const float* bp   = (const float*)d_in[2];
  const float* pos  = (const float*)d_in[3];
  const float* cle  = (const float*)d_in[4];
  const float* Wq   = (const float*)d_in[5];
  const float* Wk   = (const float*)d_in[6];
  const float* Wv   = (const float*)d_in[7];
  const float* bn1g = (const float*)d_in[8];
  const float* bn1b = (const float*)d_in[9];
  const float* Wp1  = (const float*)d_in[10];
  const float* bp1  = (const float*)d_in[11];
  const float* bn2g = (const float*)d_in[12];
  const float* bn2b = (const float*)d_in[13];
  const float* f1W  = (const float*)d_in[14];
  const float* f1b  = (const float*)d_in[15];
  const float* f2W  = (const float*)d_in[16];
  const float* f2b  = (const float*)d_in[17];
  float* ws = (float*)d_ws;
  float* out = (float*)d_out;

  hipLaunchKernelGGL(kC1, dim3(154), dim3(256), 0, stream, pos, cle, Wq, Wp1, Wp, Wv, f1W, f2W, f1b, f2b, ws);
  hipLaunchKernelGGL(kC2, dim3(150), dim3(256), 0, stream, Wk, ws);
  hipLaunchKernelGGL(kC3, dim3(52), dim3(256), 0, stream, pos, bp1, ws);
  hipLaunchKernelGGL(kA, dim3(512), dim3(512), 0, stream, x, bp, pos, ws);
  hipLaunchKernelGGL(kV, dim3(16), dim3(512), 0, stream, ws);
  hipLaunchKernelGGL(k5, dim3(256), dim3(512), 0, stream, Wp1, bn1g, bn1b, ws);
  hipLaunchKernelGGL(k7, dim3(128), dim3(256), 0, stream, bn2g, bn2b, out, ws);
}

// Round 12
// 117.083 us; speedup vs baseline: 2.2167x; 1.0019x over previous
//
#include <hip/hip_runtime.h>
#include <hip/hip_fp16.h>
#include <math.h>

#define BB 512
#define SS 100
#define DE 150
#define DM 300   // 2*D_E (also == D_IN)
#define LL 101
#define NH 2

typedef _Float16 f16x8 __attribute__((ext_vector_type(8)));
typedef float f32x4 __attribute__((ext_vector_type(4)));

// ---- ws layout (float offsets) ----
#define WS_CLS    0        // [300]
#define WS_QK     320      // [2][300]
#define WS_S0     960      // [2]
#define WS_CPOS   964      // [100][2]
#define WS_CVEC   1200     // [300]
#define WS_COLSUM 1536     // [300]
#define WS_CST0   1856     // [2]
#define WS_STATS  1860     // [0]=a1 [1]=beta1
#define WS_G      2176     // [1200][2]
#define WS_P3     5248     // [15][2][300]
#define WS_PART1  14336    // [16][2]   (kV blocks)
#define WS_PART2  15360    // [256][2]
#define WS_MSA    16384                     // [512][600]
#define WS_Y1     (WS_MSA + 512*600)        // [512][300]  ends 477184
#define WS_WPF    477184   // fp16 [40][160][8] = 102,400 B (25,600 f32)
#define WS_WVF    502784   // fp16 [2][40][320][8] = 409,600 B (102,400 f32)
#define WS_ZB16   605184   // fp16 [2][512][320] = 655,360 B (163,840 f32)
#define WS_Q0P    769024   // [10][2][300] q0 partials

// ---------------- kC1: q0 partials | Wp1 partials | cls | G | CST0 | Wpf | Wvf ----------------
// All sections restructured for lane-coalesced reads (round-11 kC1 was issue-bound on
// 64-line scattered wave loads: q0 column reads + f1W per-thread rows).
__global__ void kC1(const float* __restrict__ pos, const float* __restrict__ cle,
                    const float* __restrict__ Wq, const float* __restrict__ Wp1,
                    const float* __restrict__ Wp, const float* __restrict__ Wv,
                    const float* __restrict__ f1W, const float* __restrict__ f2W,
                    const float* __restrict__ f1b, const float* __restrict__ f2b,
                    float* __restrict__ ws) {
  __shared__ float cls[DM];
  int b = blockIdx.x, tid = threadIdx.x;
  if (b < 35) {
    for (int i = tid; i < DM; i += 256) cls[i] = (i < DE) ? cle[i] : pos[i - DE];
    __syncthreads();
  }
  if (b < 20) {
    // q0 partial: p = d-chunk of 30, h = head. Lanes sweep e (row-contiguous in Wq).
    int p = b >> 1, h = b & 1;
    const float* wqh = Wq + h * DM * DM;
    int d0 = p * 30;
    for (int e = tid; e < DM; e += 256) {
      float acc = 0.f;
#pragma unroll
      for (int d = 0; d < 30; ++d) acc += cls[d0 + d] * wqh[(d0 + d) * DM + e];
      ws[WS_Q0P + p * 600 + h * 300 + e] = acc;
    }
  } else if (b < 35) {
    int kb = b - 20;
    for (int n = tid; n < DM; n += 256) {
      float cs = 0.f, cv = 0.f;
      for (int k = kb * 60; k < kb * 60 + 60; ++k) {
        float w = Wp1[k * 300 + n];
        if (k < 600) cs += w; else cv += cls[k - 600] * w;
      }
      ws[WS_P3 + kb * 600 + n] = cs;
      ws[WS_P3 + kb * 600 + 300 + n] = cv;
    }
  } else if (b == 35) {
    for (int i = tid; i < DM; i += 256)
      ws[WS_CLS + i] = (i < DE) ? cle[i] : pos[i - DE];
  } else if (b < 111) {
    // G = f1W @ f2W, wave-per-k (4 k per wave): coalesced f1W row reads + shuffle reduce.
    int wave = tid >> 6, lane = tid & 63;
    int kbase = (b - 36) * 16 + wave * 4;
#pragma unroll
    for (int j = 0; j < 4; ++j) {
      int k = kbase + j;
      const float* r = f1W + k * 512;
      float a0 = 0.f, a1 = 0.f;
      for (int m = lane; m < 512; m += 64) {
        float a = r[m];
        float2 f2 = *(const float2*)&f2W[m * 2];
        a0 += a * f2.x; a1 += a * f2.y;
      }
      for (int o = 32; o; o >>= 1) { a0 += __shfl_xor(a0, o); a1 += __shfl_xor(a1, o); }
      if (!lane) { ws[WS_G + k * 2] = a0; ws[WS_G + k * 2 + 1] = a1; }
    }
  } else if (b == 111) {
    int wave = tid >> 6, lane = tid & 63;
    if (wave < 2) {
      float acc = 0.f;
      for (int m = lane; m < 512; m += 64) acc += f1b[m] * f2W[m * 2 + wave];
      for (int o = 32; o; o >>= 1) acc += __shfl_xor(acc, o);
      if (!lane) ws[WS_CST0 + wave] = f2b[wave] + acc;
    }
  } else if (b < 137) {
    // Wpf: fragment-ordered fp16 Wp. Wpf[kq][n][j] = Wp[kq*8+j][n]
    int idx = (b - 112) * 256 + tid;       // < 6400
    int kq = idx / 160, n = idx % 160;
    f16x8 pk;
#pragma unroll
    for (int j = 0; j < 8; ++j) {
      int k = kq * 8 + j;
      float v = (k < DM && n < DE) ? Wp[k * DE + n] : 0.f;
      pk[j] = (_Float16)v;
    }
    *(f16x8*)((char*)ws + (size_t)WS_WPF * 4 + (size_t)idx * 16) = pk;
  } else {
    // Wvf: fragment-ordered fp16 Wv, pad K->320, N->320
    int idx = (b - 137) * 256 + tid;       // < 25600
    int h = idx / 12800, rem = idx % 12800;
    int kq = rem / 320, n = rem % 320;
    f16x8 pk;
#pragma unroll
    for (int j = 0; j < 8; ++j) {
      int k = kq * 8 + j;
      float v = (k < DM && n < DM) ? Wv[h * DM * DM + k * DM + n] : 0.f;
      pk[j] = (_Float16)v;
    }
    *(f16x8*)((char*)ws + (size_t)WS_WVF * 4 + (size_t)idx * 16) = pk;
  }
}

// ---------------- kC2: qk[h][d] = Wk[h][d][:] . q0[h][:] (wave per output) ----------------
__global__ void kC2(const float* __restrict__ Wk, float* __restrict__ ws) {
  __shared__ float q0s[NH * DM];
  int tid = threadIdx.x;
  for (int i = tid; i < NH * DM; i += 256) {
    float s = 0.f;
#pragma unroll
    for (int p = 0; p < 10; ++p) s += ws[WS_Q0P + p * 600 + i];
    q0s[i] = s;
  }
  __syncthreads();
  int wave = tid >> 6, lane = tid & 63;
  int idx = blockIdx.x * 4 + wave;            // < 600
  int h = idx / DM, d = idx % DM;
  const float* w = Wk + h * DM * DM + d * DM;
  const float* q = q0s + h * DM;
  float acc = 0.f;
  for (int e = lane; e < DM; e += 64) acc += w[e] * q[e];
  for (int o = 32; o; o >>= 1) acc += __shfl_xor(acc, o);
  if (!lane) ws[WS_QK + idx] = acc;
}

// ---------------- kC3: cpos | s0 | combine(colsum,cvec) ----------------
__global__ void kC3(const float* __restrict__ pos, const float* __restrict__ bp1,
                    float* __restrict__ ws) {
  int b = blockIdx.x, tid = threadIdx.x;
  int wave = tid >> 6, lane = tid & 63;
  if (b < 50) {
    int idx = b * 4 + wave;                   // < 200, = tt*2+h
    int tt = idx >> 1, h = idx & 1;
    const float* pr = pos + (tt + 1) * DE;
    const float* qk = ws + WS_QK + h * DM + DE;
    float acc = 0.f;
    for (int j = lane; j < DE; j += 64) acc += pr[j] * qk[j];
    for (int o = 32; o; o >>= 1) acc += __shfl_xor(acc, o);
    if (!lane) ws[WS_CPOS + idx] = acc;
  } else if (b == 50) {
    if (wave < NH) {
      float acc = 0.f;
      for (int d = lane; d < DM; d += 64) acc += ws[WS_CLS + d] * ws[WS_QK + wave * DM + d];
      for (int o = 32; o; o >>= 1) acc += __shfl_xor(acc, o);
      if (!lane) ws[WS_S0 + wave] = acc;
    }
  } else {
    for (int n = tid; n < DM; n += 256) {
      float cs = 0.f, cv = bp1[n];
      for (int p = 0; p < 15; ++p) {
        cs += ws[WS_P3 + p * 600 + n];
        cv += ws[WS_P3 + p * 600 + 300 + n];
      }
      ws[WS_COLSUM + n] = cs;
      ws[WS_CVEC + n] = cv;
    }
  }
}

// ---------------- kA: MFMA h-GEMM (dbuf LDS) -> scores -> softmax -> zbar16 (global) ----
__launch_bounds__(512, 4)
__global__ void kA(const float* __restrict__ x, const float* __restrict__ bp,
                   const float* __restrict__ pos, float* __restrict__ ws) {
  __shared__ __align__(16) char smem[41600];
  __half (*hb)[DE + 2] = (__half(*)[DE + 2])smem;
  _Float16* wpt0 = (_Float16*)(smem);
  _Float16* xs0  = (_Float16*)(smem + 10240);
  _Float16* wpt1 = (_Float16*)(smem + 18240);
  _Float16* xs1  = (_Float16*)(smem + 28480);
  float* aux = (float*)(smem + 36480);

  int b = blockIdx.x, tid = threadIdx.x;
  int w = tid >> 6, lane = tid & 63;
  int l16 = lane & 15, lg = lane >> 4;
  int wm = w >> 2, wn = w & 3;
  int nnt = (wn < 3) ? 3 : 1;
  int nt0 = (wn < 3) ? wn * 3 : 9;

  const float* xb = x + b * (SS * DM);
  const char* wpf = (const char*)ws + (size_t)WS_WPF * 4;
  int rowl[4];
#pragma unroll
  for (int mt = 0; mt < 4; ++mt) {
    int r = wm * 64 + mt * 16 + l16;
    rowl[mt] = (r < SS) ? r : (SS - 1);
  }

  f32x4 acc[4][3];
#pragma unroll
  for (int mt = 0; mt < 4; ++mt)
#pragma unroll
    for (int nti = 0; nti < 3; ++nti) acc[mt][nti] = (f32x4){0.f, 0.f, 0.f, 0.f};

  float xr[4][2];
  float4 wa, wb2;

#define XLOAD(S)                                                               \
  { int kc_ = (S) * 32;                                                        \
    _Pragma("unroll")                                                          \
    for (int i_ = 0; i_ < 4; ++i_) {                                           \
      int t_ = tid + 512 * i_;                                                 \
      if (t_ < 1600) {                                                         \
        int r_ = t_ >> 4, c_ = t_ & 15, k_ = kc_ + 2 * c_;                     \
        if (k_ + 1 < DM) {                                                     \
          float2 v_ = *(const float2*)(xb + r_ * DM + k_);                     \
          xr[i_][0] = v_.x; xr[i_][1] = v_.y;                                  \
        } else {                                                               \
          xr[i_][0] = (k_ < DM) ? xb[r_ * DM + k_] : 0.f;                      \
          xr[i_][1] = 0.f;                                                     \
        } } } }

#define XWRITE(XP)                                                             \
  { _Pragma("unroll")                                                          \
    for (int i_ = 0; i_ < 4; ++i_) {                                           \
      int t_ = tid + 512 * i_;                                                 \
      if (t_ < 1600) {                                                         \
        int r_ = t_ >> 4, c_ = t_ & 15;                                        \
        *(__half2*)((char*)(XP) + r_ * 80 + c_ * 4) =                          \
            __floats2half2_rn(xr[i_][0], xr[i_][1]);                           \
      } } }

#define WLOAD(S)                                                               \
  { const char* s_ = wpf + (size_t)(S) * 10240;                                \
    wa = *(const float4*)(s_ + tid * 16);                                      \
    if (tid < 128) wb2 = *(const float4*)(s_ + (tid + 512) * 16); }

#define WWRITE(WP)                                                             \
  { *(float4*)((char*)(WP) + tid * 16) = wa;                                   \
    if (tid < 128) *(float4*)((char*)(WP) + (tid + 512) * 16) = wb2; }

  // prologue
  XLOAD(0); WLOAD(0);
  XWRITE(xs0); WWRITE(wpt0);
  __syncthreads();

  for (int s = 0; s < 10; ++s) {
    _Float16* wc = (s & 1) ? wpt1 : wpt0;
    _Float16* xc = (s & 1) ? xs1 : xs0;
    _Float16* wnx = (s & 1) ? wpt0 : wpt1;
    _Float16* xnx = (s & 1) ? xs0 : xs1;
    if (s < 9) { WLOAD(s + 1); XLOAD(s + 1); }
    f16x8 Bf[3];
#pragma unroll
    for (int nti = 0; nti < 3; ++nti)
      if (nti < nnt)
        Bf[nti] = *(const f16x8*)(wc + ((lg * 160 + (nt0 + nti) * 16 + l16) * 8));
#pragma unroll
    for (int mt = 0; mt < 4; ++mt) {
      f16x8 Af = *(const f16x8*)(xc + rowl[mt] * 40 + lg * 8);
#pragma unroll
      for (int nti = 0; nti < 3; ++nti)
        if (nti < nnt)
          acc[mt][nti] = __builtin_amdgcn_mfma_f32_16x16x32_f16(Af, Bf[nti], acc[mt][nti], 0, 0, 0);
    }
    if (s < 9) { WWRITE(wnx); XWRITE(xnx); }
    __syncthreads();
  }

  // ---- write hb = relu(acc + bp) in fp16 (aliases dead GEMM buffers) ----
#pragma unroll
  for (int nti = 0; nti < 3; ++nti) {
    if (nti < nnt) {
      int col = (nt0 + nti) * 16 + l16;
      float bpv = (col < DE) ? bp[col] : 0.f;
#pragma unroll
      for (int mt = 0; mt < 4; ++mt) {
        int rbase = wm * 64 + mt * 16 + lg * 4;
        f32x4 v = acc[mt][nti];
#pragma unroll
        for (int reg = 0; reg < 4; ++reg) {
          int row = rbase + reg;
          if (row < SS && col < DE) {
            float hv = v[reg] + bpv;
            hb[row][col] = __float2half(hv > 0.f ? hv : 0.f);
          }
        }
      }
    }
  }
  for (int i = tid; i < DM; i += 512) {
    aux[i] = ws[WS_QK + (i / DE) * DM + (i % DE)];
    aux[DM + i] = ws[WS_CLS + i];
  }
  __syncthreads();

  // ---- phase 2: scores (hb as half2) ----
  if (tid < NH * SS) {
    int hh = tid / SS, tt = tid % SS;
    const __half2* hr = (const __half2*)&hb[tt][0];
    const float* qr = &aux[hh * DE];
    float s = 0.f;
    for (int j2 = 0; j2 < DE / 2; ++j2) {
      float2 hv = __half22float2(hr[j2]);
      float2 qv = *(const float2*)&qr[2 * j2];
      s += hv.x * qv.x + hv.y * qv.y;
    }
    aux[600 + hh * LL + tt + 1] = s + ws[WS_CPOS + tt * NH + hh];
  } else if (tid < NH * SS + NH) {
    int hh = tid - NH * SS;
    aux[600 + hh * LL] = ws[WS_S0 + hh];
  }
  __syncthreads();

  // ---- phase 3: softmax (one wave per head) ----
  if (w < NH) {
    float v0 = aux[600 + w * LL + lane];
    float v1 = (lane + 64 < LL) ? aux[600 + w * LL + lane + 64] : -1e30f;
    float m = fmaxf(v0, v1);
    for (int o = 32; o; o >>= 1) m = fmaxf(m, __shfl_xor(m, o));
    float e0 = expf(v0 - m);
    float e1 = (lane + 64 < LL) ? expf(v1 - m) : 0.f;
    float s = e0 + e1;
    for (int o = 32; o; o >>= 1) s += __shfl_xor(s, o);
    float inv = 1.f / s;
    aux[802 + w * LL + lane] = e0 * inv;
    if (lane + 64 < LL) aux[802 + w * LL + lane + 64] = e1 * inv;
  }
  __syncthreads();

  // ---- phase 4: zbar -> global fp16 [h][512][320] ----
  __half* zb16 = (__half*)((char*)ws + (size_t)WS_ZB16 * 4);
  for (int o = tid; o < NH * DM; o += 512) {
    int hh = o / DM, d = o % DM;
    const float* p = &aux[802 + hh * LL];
    float acc2 = p[0] * aux[DM + d];
    if (d < DE) {
      for (int t = 1; t <= SS; ++t) acc2 += p[t] * __half2float(hb[t - 1][d]);
    } else {
      int dd = d - DE;
      for (int t = 1; t <= SS; ++t) acc2 += p[t] * pos[t * DE + dd];
    }
    zb16[((size_t)hh * 512 + b) * 320 + d] = __float2half(acc2);
  }
  if (tid < 40) {
    int hh = tid / 20, dd = 300 + tid % 20;
    zb16[((size_t)hh * 512 + b) * 320 + dd] = __float2half(0.f);
  }
}

// ---------------- kV: msa = zbar16 @ Wvf (MFMA, no LDS staging) + bn1 partials ----------------
__launch_bounds__(512, 4)
__global__ void kV(float* __restrict__ ws) {
  __shared__ float shp[2][8];
  int blk = blockIdx.x;
  int mtile = blk >> 2, nb = (blk >> 1) & 1, h = blk & 1;
  int tid = threadIdx.x;
  int w = tid >> 6, lane = tid & 63;
  int l16 = lane & 15, lg = lane >> 4;
  int wm = w >> 2, wn = w & 3;
  int nnt = (wn < 3) ? 3 : 1;
  int nt0 = (wn < 3) ? wn * 3 : 9;
  int mbase = mtile * 128;

  const __half* zb16 = (const __half*)((const char*)ws + (size_t)WS_ZB16 * 4) + (size_t)h * 512 * 320;
  const __half* wvf  = (const __half*)((const char*)ws + (size_t)WS_WVF * 4) + (size_t)h * 40 * 320 * 8;

  int brow[4];
#pragma unroll
  for (int mt = 0; mt < 4; ++mt) brow[mt] = mbase + wm * 64 + mt * 16 + l16;

  f32x4 acc[4][3];
#pragma unroll
  for (int mt = 0; mt < 4; ++mt)
#pragma unroll
    for (int nti = 0; nti < 3; ++nti) acc[mt][nti] = (f32x4){0.f, 0.f, 0.f, 0.f};

  for (int s = 0; s < 10; ++s) {
    f16x8 Bf[3];
#pragma unroll
    for (int nti = 0; nti < 3; ++nti)
      if (nti < nnt) {
        int n = nb * 160 + (nt0 + nti) * 16 + l16;
        Bf[nti] = *(const f16x8*)&wvf[((size_t)(s * 4 + lg) * 320 + n) * 8];
      }
#pragma unroll
    for (int mt = 0; mt < 4; ++mt) {
      f16x8 Af = *(const f16x8*)&zb16[(size_t)brow[mt] * 320 + s * 32 + lg * 8];
#pragma unroll
      for (int nti = 0; nti < 3; ++nti)
        if (nti < nnt)
          acc[mt][nti] = __builtin_amdgcn_mfma_f32_16x16x32_f16(Af, Bf[nti], acc[mt][nti], 0, 0, 0);
    }
  }

  float s_ = 0.f, ss_ = 0.f;
#pragma unroll
  for (int nti = 0; nti < 3; ++nti) {
    if (nti < nnt) {
      int col = nb * 160 + (nt0 + nti) * 16 + l16;
      if (col < DM) {
#pragma unroll
        for (int mt = 0; mt < 4; ++mt) {
          int rbase = mbase + wm * 64 + mt * 16 + lg * 4;
          f32x4 v = acc[mt][nti];
#pragma unroll
          for (int reg = 0; reg < 4; ++reg) {
            int row = rbase + reg;
            float val = v[reg];
            ws[WS_MSA + row * 600 + h * DM + col] = val;
            s_ += val; ss_ += val * val;
          }
        }
      }
    }
  }
  for (int o = 32; o; o >>= 1) { s_ += __shfl_xor(s_, o); ss_ += __shfl_xor(ss_, o); }
  if (!lane) { shp[0][w] = s_; shp[1][w] = ss_; }
  __syncthreads();
  if (!tid) {
    float S = 0.f, SS2 = 0.f;
    for (int i = 0; i < 8; ++i) { S += shp[0][i]; SS2 += shp[1][i]; }
    ws[WS_PART1 + blk * 2] = S;
    ws[WS_PART1 + blk * 2 + 1] = SS2;
  }
}

// ---------------- k5: bn1 finalize + y1 (split-K x2) + bn2 per-block partial ----------------
__launch_bounds__(512)
__global__ void k5(const float* __restrict__ Wp1, const float* __restrict__ g1,
                   const float* __restrict__ b1, float* __restrict__ ws) {
  __shared__ float ab[2][600];
  __shared__ float part[2][2][300];
  __shared__ float sh[2][8];
  __shared__ float s_a1, s_b1;
  int b0 = blockIdx.x * 2, tid = threadIdx.x;
  int wv = tid >> 6, ln = tid & 63;
  for (int i = tid; i < 1200; i += 512) ab[i / 600][i % 600] = ws[WS_MSA + b0 * 600 + i];
  {
    float s = 0.f, ss = 0.f;
    if (tid < 16) { s = ws[WS_PART1 + tid * 2]; ss = ws[WS_PART1 + tid * 2 + 1]; }
    for (int o = 32; o; o >>= 1) { s += __shfl_xor(s, o); ss += __shfl_xor(ss, o); }
    if (!ln) { sh[0][wv] = s; sh[1][wv] = ss; }
  }
  __syncthreads();
  if (!tid) {
    float S = 0.f, SS2 = 0.f;
    for (int i = 0; i < 8; ++i) { S += sh[0][i]; SS2 += sh[1][i]; }
    float n = (float)(BB * 600);
    float mean = S / n, var = SS2 / n - mean * mean;
    float a = (1.f / sqrtf(var + 1e-5f)) * g1[0];
    s_a1 = a; s_b1 = b1[0] - a * mean;
    if (blockIdx.x == 0) { ws[WS_STATS + 0] = a; ws[WS_STATS + 1] = s_b1; }
  }
  __syncthreads();
  int g = tid >> 8, t = tid & 255;
  int kbeg = g * 300, kend = kbeg + 300;
  for (int n = t; n < 300; n += 256) {
    float a0 = 0.f, a1v = 0.f;
    for (int k = kbeg; k < kend; ++k) {
      float wq = Wp1[k * 300 + n];
      a0 += ab[0][k] * wq;
      a1v += ab[1][k] * wq;
    }
    part[g][0][n] = a0;
    part[g][1][n] = a1v;
  }
  __syncthreads();
  float a1 = s_a1, beta1 = s_b1;
  float s2 = 0.f, ss2 = 0.f;
  for (int n = tid; n < 300; n += 512) {
    float c = beta1 * ws[WS_COLSUM + n] + ws[WS_CVEC + n];
    float v0 = a1 * (part[0][0][n] + part[1][0][n]) + c;
    float v1 = a1 * (part[0][1][n] + part[1][1][n]) + c;
    v0 = v0 > 0.f ? v0 : 0.f;
    v1 = v1 > 0.f ? v1 : 0.f;
    ws[WS_Y1 + b0 * 300 + n] = v0;
    ws[WS_Y1 + (b0 + 1) * 300 + n] = v1;
    s2 += v0 + v1; ss2 += v0 * v0 + v1 * v1;
  }
  for (int o = 32; o; o >>= 1) { s2 += __shfl_xor(s2, o); ss2 += __shfl_xor(ss2, o); }
  if (!ln) { sh[0][wv] = s2; sh[1][wv] = ss2; }
  __syncthreads();
  if (!tid) {
    float S = 0.f, SS2 = 0.f;
    for (int i = 0; i < 8; ++i) { S += sh[0][i]; SS2 += sh[1][i]; }
    ws[WS_PART2 + blockIdx.x * 2] = S;
    ws[WS_PART2 + blockIdx.x * 2 + 1] = SS2;
  }
}

// ---------------- k7: bn2 finalize + consts + out (wave per batch) ----------------
__launch_bounds__(256)
__global__ void k7(const float* __restrict__ g2, const float* __restrict__ b2,
                   float* __restrict__ out, const float* __restrict__ ws) {
  __shared__ float Gs[2400];
  __shared__ float sh[2][4];
  __shared__ float cc[4];   // a2, b2s, c0, c1
  int tid = threadIdx.x, wv = tid >> 6, ln = tid & 63;
  for (int i = tid; i < 2400; i += 256) Gs[i] = ws[WS_G + i];
  {
    float s = ws[WS_PART2 + tid * 2], ss = ws[WS_PART2 + tid * 2 + 1];
    for (int o = 32; o; o >>= 1) { s += __shfl_xor(s, o); ss += __shfl_xor(ss, o); }
    if (!ln) { sh[0][wv] = s; sh[1][wv] = ss; }
  }
  __syncthreads();
  if (!tid) {
    float S = 0.f, SS2 = 0.f;
    for (int i = 0; i < 4; ++i) { S += sh[0][i]; SS2 += sh[1][i]; }
    float n = (float)(BB * 300);
    float mean = S / n, var = SS2 / n - mean * mean;
    float a = (1.f / sqrtf(var + 1e-5f)) * g2[0];
    cc[0] = a; cc[1] = b2[0] - a * mean;
  }
  __syncthreads();
  if (tid < 2) {
    int c = tid;
    float sg1 = 0.f, sg2 = 0.f, sg3 = 0.f;
    for (int k = 0; k < 300; ++k) sg1 += Gs[k * 2 + c];
    for (int k = 300; k < 900; ++k) sg2 += Gs[k * 2 + c];
    for (int j = 0; j < 300; ++j) sg3 += ws[WS_CLS + j] * Gs[(900 + j) * 2 + c];
    cc[2 + c] = ws[WS_CST0 + c] + sg3 + cc[1] * sg1 + ws[WS_STATS + 1] * sg2;
  }
  __syncthreads();
  int b = blockIdx.x * 4 + wv;
  float a1 = ws[WS_STATS + 0], a2 = cc[0];
  const float* y1 = ws + WS_Y1 + b * 300;
  const float* ms = ws + WS_MSA + b * 600;
  float o0 = 0.f, o1 = 0.f, p0 = 0.f, p1 = 0.f;
  for (int k = ln; k < 300; k += 64) { float v = y1[k]; o0 += v * Gs[k * 2]; o1 += v * Gs[k * 2 + 1]; }
  for (int j = ln; j < 600; j += 64) { float v = ms[j]; p0 += v * Gs[(300 + j) * 2]; p1 += v * Gs[(300 + j) * 2 + 1]; }
  for (int o = 32; o; o >>= 1) {
    o0 += __shfl_xor(o0, o); o1 += __shfl_xor(o1, o);
    p0 += __shfl_xor(p0, o); p1 += __shfl_xor(p1, o);
  }
  if (!ln) {
    out[b * 2] = a2 * o0 + a1 * p0 + cc[2];
    out[b * 2 + 1] = a2 * o1 + a1 * p1 + cc[3];
  }
}

extern "C" void kernel_launch(void* const* d_in, const int* in_sizes, int n_in,
                              void* d_out, int out_size, void* d_ws, size_t ws_size,
                              hipStream_t stream) {
  const float* x    = (const float*)d_in[0];
  const float* Wp   = (const float*)d_in[1];
  const float* bp   = (const float*)d_in[2];
  const float* pos  = (const float*)d_in[3];
  const float* cle  = (const float*)d_in[4];
  const float* Wq   = (const float*)d_in[5];
  const float* Wk   = (const float*)d_in[6];
  const float* Wv   = (const float*)d_in[7];
  const float* bn1g = (const float*)d_in[8];
  const float* bn1b = (const float*)d_in[9];
  const float* Wp1  = (const float*)d_in[10];
  const float* bp1  = (const float*)d_in[11];
  const float* bn2g = (const float*)d_in[12];
  const float* bn2b = (const float*)d_in[13];
  const float* f1W  = (const float*)d_in[14];
  const float* f1b  = (const float*)d_in[15];
  const float* f2W  = (const float*)d_in[16];
  const float* f2b  = (const float*)d_in[17];
  float* ws = (float*)d_ws;
  float* out = (float*)d_out;

  hipLaunchKernelGGL(kC1, dim3(237), dim3(256), 0, stream, pos, cle, Wq, Wp1, Wp, Wv, f1W, f2W, f1b, f2b, ws);
  hipLaunchKernelGGL(kC2, dim3(150), dim3(256), 0, stream, Wk, ws);
  hipLaunchKernelGGL(kC3, dim3(52), dim3(256), 0, stream, pos, bp1, ws);
  hipLaunchKernelGGL(kA, dim3(512), dim3(512), 0, stream, x, bp, pos, ws);
  hipLaunchKernelGGL(kV, dim3(16), dim3(512), 0, stream, ws);
  hipLaunchKernelGGL(k5, dim3(256), dim3(512), 0, stream, Wp1, bn1g, bn1b, ws);
  hipLaunchKernelGGL(k7, dim3(128), dim3(256), 0, stream, bn2g, bn2b, out, ws);
}